// Round 1
// baseline (2066.725 us; speedup 1.0000x reference)
//
#include <hip/hip_runtime.h>
#include <stdint.h>

typedef unsigned long long u64;

#define BB 4
#define NN 32768
#define CC 3
#define PRE 4096
#define POST 512
#define TH 0.7f

// ---- workspace layout (bytes) ----
// key   [B][N]  u64      : B*N*8      = 1,048,576
// kstar [B]     u64      : 64 (padded)
// cnt   [B]     u32      : 64 (padded)
// selk  [B][PRE] u64     : 131,072
// bf    [B][5][PRE] f32  : 327,680   (x1,x2,y1,y2,area SoA)
// sidx  [B][PRE] i32     : 65,536
// ssc   [B][PRE] f32     : 65,536
// sup   [B][PRE][64] u64 : 8,388,608
// keep  [B][64] u64      : 2,048
// total ~ 10.0 MiB

__device__ __forceinline__ uint32_t f2u(float f) {
    uint32_t b = __float_as_uint(f);
    return (b & 0x80000000u) ? ~b : (b | 0x80000000u);
}
__device__ __forceinline__ float u2f(uint32_t u) {
    uint32_t b = (u & 0x80000000u) ? (u & 0x7FFFFFFFu) : ~u;
    return __uint_as_float(b);
}

// 1) per-element key = (orderable(score) << 32) | ~index  (distinct keys => exact top_k tie-break)
__global__ void k_keys(const float* __restrict__ cls, u64* __restrict__ key) {
    int gid = blockIdx.x * blockDim.x + threadIdx.x;
    if (gid >= BB * NN) return;
    const float* p = cls + (size_t)gid * CC;
    float s = fmaxf(fmaxf(p[0], p[1]), p[2]);
    int n = gid & (NN - 1);
    key[gid] = ((u64)f2u(s) << 32) | (uint32_t)(~(uint32_t)n);
}

__global__ void k_init(uint32_t* cnt) {
    if (threadIdx.x < BB) cnt[threadIdx.x] = 0;
}

// 2a) 8-pass MSB radix select: kstar[b] = exact 4096-th largest key of item b
__global__ void k_select(const u64* __restrict__ key, u64* __restrict__ kstar) {
    int b = blockIdx.x;
    const u64* kb = key + (size_t)b * NN;
    __shared__ uint32_t hist[256];
    __shared__ u64 s_prefix;
    __shared__ uint32_t s_k;
    if (threadIdx.x == 0) { s_prefix = 0; s_k = PRE; }
    __syncthreads();
    for (int pass = 0; pass < 8; ++pass) {
        hist[threadIdx.x] = 0;   // blockDim == 256
        __syncthreads();
        u64 prefix = s_prefix;
        int hi = 8 * pass;
        for (int i = threadIdx.x; i < NN; i += blockDim.x) {
            u64 k = kb[i];
            bool match = (pass == 0) || ((k >> (64 - hi)) == prefix);
            if (match) {
                uint32_t d = (uint32_t)((k >> (56 - hi)) & 255u);
                atomicAdd(&hist[d], 1u);
            }
        }
        __syncthreads();
        if (threadIdx.x == 0) {
            uint32_t kneed = s_k, cum = 0; int chosen = 0;
            for (int d = 255; d >= 0; --d) {
                if (kneed <= cum + hist[d]) { chosen = d; break; }
                cum += hist[d];
            }
            s_k = kneed - cum;
            s_prefix = (prefix << 8) | (u64)(uint32_t)chosen;
        }
        __syncthreads();
    }
    if (threadIdx.x == 0) kstar[b] = s_prefix;
}

// 2b) compact: keys >= kstar (exactly PRE of them, keys distinct)
__global__ void k_compact(const u64* __restrict__ key, const u64* __restrict__ kstar,
                          uint32_t* __restrict__ cnt, u64* __restrict__ selk) {
    int gid = blockIdx.x * blockDim.x + threadIdx.x;
    if (gid >= BB * NN) return;
    int b = gid >> 15;
    u64 k = key[gid];
    if (k >= kstar[b]) {
        uint32_t pos = atomicAdd(&cnt[b], 1u);
        selk[(size_t)b * PRE + pos] = k;
    }
}

// 3) bitonic sort (descending) of 4096 keys in LDS; derive orig idx, score, box features
__global__ void __launch_bounds__(1024) k_sort(const u64* __restrict__ selk,
                                               const float* __restrict__ box,
                                               int* __restrict__ sidx, float* __restrict__ ssc,
                                               float* __restrict__ bf) {
    int b = blockIdx.x;
    __shared__ u64 s[PRE];
    const u64* sk = selk + (size_t)b * PRE;
    for (int i = threadIdx.x; i < PRE; i += blockDim.x) s[i] = sk[i];
    __syncthreads();
    for (int k = 2; k <= PRE; k <<= 1) {
        for (int j = k >> 1; j > 0; j >>= 1) {
            for (int i = threadIdx.x; i < PRE; i += blockDim.x) {
                int ixj = i ^ j;
                if (ixj > i) {
                    u64 a = s[i], c = s[ixj];
                    bool desc = ((i & k) == 0);
                    if (desc ? (a < c) : (a > c)) { s[i] = c; s[ixj] = a; }
                }
            }
            __syncthreads();
        }
    }
    float* bfb = bf + (size_t)b * 5 * PRE;
    for (int r = threadIdx.x; r < PRE; r += blockDim.x) {
        u64 kk = s[r];
        int n = (int)(~(uint32_t)(kk & 0xFFFFFFFFull));
        float sc = u2f((uint32_t)(kk >> 32));
        sidx[b * PRE + r] = n;
        ssc[b * PRE + r] = sc;
        const float* bp = box + ((size_t)b * NN + n) * 7;
        float x = bp[0], y = bp[1], dx = bp[3], dy = bp[4];
        bfb[0 * PRE + r] = x - dx * 0.5f;
        bfb[1 * PRE + r] = x + dx * 0.5f;
        bfb[2 * PRE + r] = y - dy * 0.5f;
        bfb[3 * PRE + r] = y + dy * 0.5f;
        bfb[4 * PRE + r] = dx * dy;
    }
}

// 4) suppression bitmask: sup[b][i][w] bit jj = (iou(i, 64w+jj) > TH && col > i)
__global__ void k_iou(const float* __restrict__ bf, u64* __restrict__ sup) {
    int gid = blockIdx.x * blockDim.x + threadIdx.x;   // B*PRE*64 threads
    int w = gid & 63;
    int i = (gid >> 6) & (PRE - 1);
    int b = gid >> 18;
    const float* bfb = bf + (size_t)b * 5 * PRE;
    float x1 = bfb[0 * PRE + i], x2 = bfb[1 * PRE + i];
    float y1 = bfb[2 * PRE + i], y2 = bfb[3 * PRE + i];
    float ar = bfb[4 * PRE + i];
    u64 m = 0;
    int j0 = w * 64;
    for (int jj = 0; jj < 64; ++jj) {
        int j = j0 + jj;
        float ix = fminf(x2, bfb[1 * PRE + j]) - fmaxf(x1, bfb[0 * PRE + j]);
        ix = fmaxf(ix, 0.0f);
        float iy = fminf(y2, bfb[3 * PRE + j]) - fmaxf(y1, bfb[2 * PRE + j]);
        iy = fmaxf(iy, 0.0f);
        float inter = __fmul_rn(ix, iy);               // block FMA contraction (match JAX rounding)
        float uni = (ar + bfb[4 * PRE + j]) - inter;
        float iou = inter / fmaxf(uni, 1e-6f);
        if (iou > TH && j > i) m |= (1ull << jj);
    }
    sup[(size_t)gid] = m;
}

// 5) sequential greedy scan: one wave per item, lane w owns removed-word w, 8-deep prefetch
__global__ void k_scan(const u64* __restrict__ sup, u64* __restrict__ keep) {
    int b = blockIdx.x;
    int lane = threadIdx.x;   // 64 threads = 1 wave
    const u64* sb = sup + (size_t)b * PRE * 64;
    u64 removed = 0;
    u64 buf[8];
#pragma unroll
    for (int p = 0; p < 8; ++p) buf[p] = sb[(size_t)p * 64 + lane];
    for (int ib = 0; ib < PRE; ib += 8) {
#pragma unroll
        for (int p = 0; p < 8; ++p) {
            int i = ib + p;
            u64 cur = buf[p];
            int nx = i + 8;
            if (nx < PRE) buf[p] = sb[(size_t)nx * 64 + lane];
            u64 rw = __shfl(removed, i >> 6, 64);
            if (!((rw >> (i & 63)) & 1ull)) removed |= cur;
        }
    }
    keep[b * 64 + lane] = ~removed;
}

// 6) outputs: destination = position in argsort(where(keep, rank, PRE)); write rois/scores/labels
__global__ void __launch_bounds__(512) k_out(const u64* __restrict__ keepm,
                                             const int* __restrict__ sidx,
                                             const float* __restrict__ ssc,
                                             const float* __restrict__ box,
                                             const float* __restrict__ cls,
                                             float* __restrict__ out) {
    int b = blockIdx.x;
    __shared__ uint32_t wpre[65];
    const u64* km = keepm + b * 64;
    if (threadIdx.x == 0) {
        uint32_t c = 0;
        for (int w = 0; w < 64; ++w) { wpre[w] = c; c += (uint32_t)__popcll(km[w]); }
        wpre[64] = c;
    }
    __syncthreads();
    uint32_t nkeep = wpre[64];
    for (int r = threadIdx.x; r < PRE; r += blockDim.x) {
        int w = r >> 6, bit = r & 63;
        u64 word = km[w];
        bool kept = (word >> bit) & 1ull;
        u64 mask = bit ? ((1ull << bit) - 1ull) : 0ull;
        uint32_t before = wpre[w] + (uint32_t)__popcll(word & mask);
        uint32_t d = kept ? before : (nkeep + (uint32_t)r - before);
        if (d < POST) {
            float* ro = out + ((size_t)b * POST + d) * 7;
            float* so = out + (size_t)BB * POST * 7 + b * POST + d;
            float* lo = out + (size_t)BB * POST * 8 + b * POST + d;
            if (kept) {
                int n = sidx[b * PRE + r];
                const float* bp = box + ((size_t)b * NN + n) * 7;
#pragma unroll
                for (int t = 0; t < 7; ++t) ro[t] = bp[t];
                *so = ssc[b * PRE + r];
                const float* cp = cls + ((size_t)b * NN + n) * CC;
                float c0 = cp[0], c1 = cp[1], c2 = cp[2];
                int lbl = 0; float bst = c0;
                if (c1 > bst) { bst = c1; lbl = 1; }
                if (c2 > bst) { lbl = 2; }
                *lo = (float)(lbl + 1);
            } else {
#pragma unroll
                for (int t = 0; t < 7; ++t) ro[t] = 0.0f;
                *so = 0.0f;
                *lo = 1.0f;
            }
        }
    }
}

extern "C" void kernel_launch(void* const* d_in, const int* in_sizes, int n_in,
                              void* d_out, int out_size, void* d_ws, size_t ws_size,
                              hipStream_t stream) {
    const float* cls = (const float*)d_in[0];   // (4, 32768, 3)
    const float* box = (const float*)d_in[1];   // (4, 32768, 7)
    float* out = (float*)d_out;                 // 18432 floats

    char* ws = (char*)d_ws;
    size_t OFF_KEY   = 0;
    size_t OFF_KSTAR = OFF_KEY + (size_t)BB * NN * 8;
    size_t OFF_CNT   = OFF_KSTAR + 64;
    size_t OFF_SELK  = OFF_CNT + 64;
    size_t OFF_BF    = OFF_SELK + (size_t)BB * PRE * 8;
    size_t OFF_SIDX  = OFF_BF + (size_t)BB * 5 * PRE * 4;
    size_t OFF_SSC   = OFF_SIDX + (size_t)BB * PRE * 4;
    size_t OFF_SUP   = OFF_SSC + (size_t)BB * PRE * 4;
    size_t OFF_KEEP  = OFF_SUP + (size_t)BB * PRE * 64 * 8;

    u64*      key   = (u64*)(ws + OFF_KEY);
    u64*      kstar = (u64*)(ws + OFF_KSTAR);
    uint32_t* cnt   = (uint32_t*)(ws + OFF_CNT);
    u64*      selk  = (u64*)(ws + OFF_SELK);
    float*    bf    = (float*)(ws + OFF_BF);
    int*      sidx  = (int*)(ws + OFF_SIDX);
    float*    ssc   = (float*)(ws + OFF_SSC);
    u64*      sup   = (u64*)(ws + OFF_SUP);
    u64*      keepm = (u64*)(ws + OFF_KEEP);

    k_init<<<1, 64, 0, stream>>>(cnt);
    k_keys<<<(BB * NN) / 256, 256, 0, stream>>>(cls, key);
    k_select<<<BB, 256, 0, stream>>>(key, kstar);
    k_compact<<<(BB * NN) / 256, 256, 0, stream>>>(key, kstar, cnt, selk);
    k_sort<<<BB, 1024, 0, stream>>>(selk, box, sidx, ssc, bf);
    k_iou<<<(BB * PRE * 64) / 256, 256, 0, stream>>>(bf, sup);
    k_scan<<<BB, 64, 0, stream>>>(sup, keepm);
    k_out<<<BB, 512, 0, stream>>>(keepm, sidx, ssc, box, cls, out);
}

// Round 2
// 544.406 us; speedup vs baseline: 3.7963x; 3.7963x over previous
//
#include <hip/hip_runtime.h>
#include <stdint.h>

typedef unsigned long long u64;

#define BB 4
#define NN 32768
#define CC 3
#define PRE 4096
#define POST 512
#define TH 0.7f
#define ROWS_A 1024   // phase-A suppression rows (covers keep-rate >= 0.5)

// ---- workspace layout (bytes) ----
// key   [B][N]  u64      : 1,048,576
// kstar [B]     u64      : 64
// cnt   [B]     u32      : 64
// selk  [B][PRE] u64     : 131,072
// bf    [B][5][PRE] f32  : 327,680   (x1,x2,y1,y2,area SoA)
// sidx  [B][PRE] i32     : 65,536
// ssc   [B][PRE] f32     : 65,536
// sup   [B][PRE][64] u64 : 8,388,608
// keep  [B][64] u64      : 2,048     (raw removed if flag==0, final masked keep if 1)
// flag  [B]     u32      : 64

__device__ __forceinline__ uint32_t f2u(float f) {
    uint32_t b = __float_as_uint(f);
    return (b & 0x80000000u) ? ~b : (b | 0x80000000u);
}
__device__ __forceinline__ float u2f(uint32_t u) {
    uint32_t b = (u & 0x80000000u) ? (u & 0x7FFFFFFFu) : ~u;
    return __uint_as_float(b);
}

// 1) per-element key = (orderable(score) << 32) | ~index  (distinct keys => exact top_k tie-break)
__global__ void k_keys(const float* __restrict__ cls, u64* __restrict__ key) {
    int gid = blockIdx.x * blockDim.x + threadIdx.x;
    if (gid >= BB * NN) return;
    const float* p = cls + (size_t)gid * CC;
    float s = fmaxf(fmaxf(p[0], p[1]), p[2]);
    int n = gid & (NN - 1);
    key[gid] = ((u64)f2u(s) << 32) | (uint32_t)(~(uint32_t)n);
}

__global__ void k_init(uint32_t* cnt) {
    if (threadIdx.x < BB) cnt[threadIdx.x] = 0;
}

// 2a) 8-pass MSB radix select: kstar[b] = exact 4096-th largest key of item b
__global__ void k_select(const u64* __restrict__ key, u64* __restrict__ kstar) {
    int b = blockIdx.x;
    const u64* kb = key + (size_t)b * NN;
    __shared__ uint32_t hist[256];
    __shared__ u64 s_prefix;
    __shared__ uint32_t s_k;
    if (threadIdx.x == 0) { s_prefix = 0; s_k = PRE; }
    __syncthreads();
    for (int pass = 0; pass < 8; ++pass) {
        hist[threadIdx.x] = 0;   // blockDim == 256
        __syncthreads();
        u64 prefix = s_prefix;
        int hi = 8 * pass;
        for (int i = threadIdx.x; i < NN; i += blockDim.x) {
            u64 k = kb[i];
            bool match = (pass == 0) || ((k >> (64 - hi)) == prefix);
            if (match) {
                uint32_t d = (uint32_t)((k >> (56 - hi)) & 255u);
                atomicAdd(&hist[d], 1u);
            }
        }
        __syncthreads();
        if (threadIdx.x == 0) {
            uint32_t kneed = s_k, cum = 0; int chosen = 0;
            for (int d = 255; d >= 0; --d) {
                if (kneed <= cum + hist[d]) { chosen = d; break; }
                cum += hist[d];
            }
            s_k = kneed - cum;
            s_prefix = (prefix << 8) | (u64)(uint32_t)chosen;
        }
        __syncthreads();
    }
    if (threadIdx.x == 0) kstar[b] = s_prefix;
}

// 2b) compact: keys >= kstar (exactly PRE of them, keys distinct)
__global__ void k_compact(const u64* __restrict__ key, const u64* __restrict__ kstar,
                          uint32_t* __restrict__ cnt, u64* __restrict__ selk) {
    int gid = blockIdx.x * blockDim.x + threadIdx.x;
    if (gid >= BB * NN) return;
    int b = gid >> 15;
    u64 k = key[gid];
    if (k >= kstar[b]) {
        uint32_t pos = atomicAdd(&cnt[b], 1u);
        selk[(size_t)b * PRE + pos] = k;
    }
}

// 3) bitonic sort (descending) of 4096 keys in LDS; derive orig idx, score, box features
__global__ void __launch_bounds__(1024) k_sort(const u64* __restrict__ selk,
                                               const float* __restrict__ box,
                                               int* __restrict__ sidx, float* __restrict__ ssc,
                                               float* __restrict__ bf) {
    int b = blockIdx.x;
    __shared__ u64 s[PRE];
    const u64* sk = selk + (size_t)b * PRE;
    for (int i = threadIdx.x; i < PRE; i += blockDim.x) s[i] = sk[i];
    __syncthreads();
    for (int k = 2; k <= PRE; k <<= 1) {
        for (int j = k >> 1; j > 0; j >>= 1) {
            for (int i = threadIdx.x; i < PRE; i += blockDim.x) {
                int ixj = i ^ j;
                if (ixj > i) {
                    u64 a = s[i], c = s[ixj];
                    bool desc = ((i & k) == 0);
                    if (desc ? (a < c) : (a > c)) { s[i] = c; s[ixj] = a; }
                }
            }
            __syncthreads();
        }
    }
    float* bfb = bf + (size_t)b * 5 * PRE;
    for (int r = threadIdx.x; r < PRE; r += blockDim.x) {
        u64 kk = s[r];
        int n = (int)(~(uint32_t)(kk & 0xFFFFFFFFull));
        float sc = u2f((uint32_t)(kk >> 32));
        sidx[b * PRE + r] = n;
        ssc[b * PRE + r] = sc;
        const float* bp = box + ((size_t)b * NN + n) * 7;
        float x = bp[0], y = bp[1], dx = bp[3], dy = bp[4];
        bfb[0 * PRE + r] = x - dx * 0.5f;
        bfb[1 * PRE + r] = x + dx * 0.5f;
        bfb[2 * PRE + r] = y - dy * 0.5f;
        bfb[3 * PRE + r] = y + dy * 0.5f;
        bfb[4 * PRE + r] = dx * dy;
    }
}

// 4) suppression rows [START,END): one wave per row i, lane = column within 64-wide group,
//    word w of row i = __ballot over lanes at j = w*64+lane. Coalesced loads.
//    CHECK_FLAG: per-item early-out when scan already finished.
template<int START, int END, bool CHECK_FLAG>
__global__ void k_iou_t(const float* __restrict__ bf, u64* __restrict__ sup,
                        const uint32_t* __restrict__ flag) {
    const int bpi = (END - START) / 4;       // blocks per item (4 waves/block)
    int b = blockIdx.x / bpi;
    if (CHECK_FLAG && flag[b]) return;
    int wave = threadIdx.x >> 6;
    int lane = threadIdx.x & 63;
    int i = START + (blockIdx.x % bpi) * 4 + wave;
    const float* bfb = bf + (size_t)b * 5 * PRE;
    float x1 = bfb[0 * PRE + i], x2 = bfb[1 * PRE + i];
    float y1 = bfb[2 * PRE + i], y2 = bfb[3 * PRE + i];
    float ar = bfb[4 * PRE + i];
    u64 myword = 0;
    for (int jw = 0; jw < 64; ++jw) {
        int j = jw * 64 + lane;
        float jx1 = bfb[0 * PRE + j], jx2 = bfb[1 * PRE + j];
        float jy1 = bfb[2 * PRE + j], jy2 = bfb[3 * PRE + j];
        float jar = bfb[4 * PRE + j];
        float ix = fminf(x2, jx2) - fmaxf(x1, jx1);
        ix = fmaxf(ix, 0.0f);
        float iy = fminf(y2, jy2) - fmaxf(y1, jy1);
        iy = fmaxf(iy, 0.0f);
        float inter = __fmul_rn(ix, iy);            // block FMA contraction (match np rounding)
        float uni = (ar + jar) - inter;
        float iou = inter / fmaxf(uni, 1e-6f);
        u64 bal = __ballot((iou > TH) && (j > i));
        if (jw == lane) myword = bal;
    }
    sup[((size_t)b * PRE + i) * 64 + lane] = myword;
}

__device__ __forceinline__ uint32_t kept_count(u64 removed, int words, int lane) {
    int v = (lane < words) ? __popcll(~removed) : 0;
#pragma unroll
    for (int off = 32; off > 0; off >>= 1) v += __shfl_xor(v, off, 64);
    return (uint32_t)v;
}

// 5) greedy scan rows [START,END): 1 wave/item, lane w owns removed-word w.
//    32-row register chunks, double-buffered; early exit once POST kept rows found
//    (bits <= i are final after row i; later ranks can't enter the first POST outputs).
template<int START, int END>
__global__ void k_scan_t(const u64* __restrict__ sup, u64* __restrict__ keepm,
                         uint32_t* __restrict__ flag) {
    const int CH = 32;
    int b = blockIdx.x;
    int lane = threadIdx.x;   // 64 threads = 1 wave
    if (START > 0) { if (flag[b]) return; }
    u64 removed = (START > 0) ? keepm[b * 64 + lane] : 0ull;
    const u64* sb = sup + (size_t)b * PRE * 64;

    u64 bufA[CH], bufB[CH];
#pragma unroll
    for (int p = 0; p < CH; ++p) bufA[p] = sb[(size_t)(START + p) * 64 + lane];

    bool fin = false;
    int S = END;
    for (int g = START; g < END; g += 64) {
        // prefetch rows [g+32, g+64) into bufB (always valid: END-g >= 64)
#pragma unroll
        for (int p = 0; p < CH; ++p) bufB[p] = sb[(size_t)(g + CH + p) * 64 + lane];
        // process rows [g, g+32) from bufA
#pragma unroll
        for (int p = 0; p < CH; ++p) {
            int i = g + p;
            u64 rw = __shfl(removed, i >> 6, 64);
            if (!((rw >> (i & 63)) & 1ull)) removed |= bufA[p];
        }
        // prefetch rows [g+64, g+96) into bufA
        if (g + 64 < END) {
#pragma unroll
            for (int p = 0; p < CH; ++p) bufA[p] = sb[(size_t)(g + 64 + p) * 64 + lane];
        }
        // process rows [g+32, g+64) from bufB
#pragma unroll
        for (int p = 0; p < CH; ++p) {
            int i = g + CH + p;
            u64 rw = __shfl(removed, i >> 6, 64);
            if (!((rw >> (i & 63)) & 1ull)) removed |= bufB[p];
        }
        // exact kept count over finalized rows [0, g+64)
        uint32_t kept = kept_count(removed, (g + 64) >> 6, lane);
        if (kept >= POST) { S = g + 64; fin = true; break; }
    }

    if (!fin && END < PRE) {
        // resume state for phase B
        keepm[b * 64 + lane] = removed;
        if (lane == 0) flag[b] = 0;
    } else {
        // final: masked keep (bits >= S zeroed; S multiple of 64)
        int words = S >> 6;
        keepm[b * 64 + lane] = (lane < words) ? ~removed : 0ull;
        if (lane == 0) flag[b] = 1;
    }
}

// 6) outputs: destination = position in argsort(where(keep, rank, PRE)); write rois/scores/labels
__global__ void __launch_bounds__(512) k_out(const u64* __restrict__ keepm,
                                             const int* __restrict__ sidx,
                                             const float* __restrict__ ssc,
                                             const float* __restrict__ box,
                                             const float* __restrict__ cls,
                                             float* __restrict__ out) {
    int b = blockIdx.x;
    __shared__ uint32_t wpre[65];
    const u64* km = keepm + b * 64;
    if (threadIdx.x == 0) {
        uint32_t c = 0;
        for (int w = 0; w < 64; ++w) { wpre[w] = c; c += (uint32_t)__popcll(km[w]); }
        wpre[64] = c;
    }
    __syncthreads();
    uint32_t nkeep = wpre[64];
    for (int r = threadIdx.x; r < PRE; r += blockDim.x) {
        int w = r >> 6, bit = r & 63;
        u64 word = km[w];
        bool kept = (word >> bit) & 1ull;
        u64 mask = bit ? ((1ull << bit) - 1ull) : 0ull;
        uint32_t before = wpre[w] + (uint32_t)__popcll(word & mask);
        uint32_t d = kept ? before : (nkeep + (uint32_t)r - before);
        if (d < POST) {
            float* ro = out + ((size_t)b * POST + d) * 7;
            float* so = out + (size_t)BB * POST * 7 + b * POST + d;
            float* lo = out + (size_t)BB * POST * 8 + b * POST + d;
            if (kept) {
                int n = sidx[b * PRE + r];
                const float* bp = box + ((size_t)b * NN + n) * 7;
#pragma unroll
                for (int t = 0; t < 7; ++t) ro[t] = bp[t];
                *so = ssc[b * PRE + r];
                const float* cp = cls + ((size_t)b * NN + n) * CC;
                float c0 = cp[0], c1 = cp[1], c2 = cp[2];
                int lbl = 0; float bst = c0;
                if (c1 > bst) { bst = c1; lbl = 1; }
                if (c2 > bst) { lbl = 2; }
                *lo = (float)(lbl + 1);
            } else {
#pragma unroll
                for (int t = 0; t < 7; ++t) ro[t] = 0.0f;
                *so = 0.0f;
                *lo = 1.0f;
            }
        }
    }
}

extern "C" void kernel_launch(void* const* d_in, const int* in_sizes, int n_in,
                              void* d_out, int out_size, void* d_ws, size_t ws_size,
                              hipStream_t stream) {
    const float* cls = (const float*)d_in[0];   // (4, 32768, 3)
    const float* box = (const float*)d_in[1];   // (4, 32768, 7)
    float* out = (float*)d_out;                 // 18432 floats

    char* ws = (char*)d_ws;
    size_t OFF_KEY   = 0;
    size_t OFF_KSTAR = OFF_KEY + (size_t)BB * NN * 8;
    size_t OFF_CNT   = OFF_KSTAR + 64;
    size_t OFF_SELK  = OFF_CNT + 64;
    size_t OFF_BF    = OFF_SELK + (size_t)BB * PRE * 8;
    size_t OFF_SIDX  = OFF_BF + (size_t)BB * 5 * PRE * 4;
    size_t OFF_SSC   = OFF_SIDX + (size_t)BB * PRE * 4;
    size_t OFF_SUP   = OFF_SSC + (size_t)BB * PRE * 4;
    size_t OFF_KEEP  = OFF_SUP + (size_t)BB * PRE * 64 * 8;
    size_t OFF_FLAG  = OFF_KEEP + (size_t)BB * 64 * 8;

    u64*      key   = (u64*)(ws + OFF_KEY);
    u64*      kstar = (u64*)(ws + OFF_KSTAR);
    uint32_t* cnt   = (uint32_t*)(ws + OFF_CNT);
    u64*      selk  = (u64*)(ws + OFF_SELK);
    float*    bf    = (float*)(ws + OFF_BF);
    int*      sidx  = (int*)(ws + OFF_SIDX);
    float*    ssc   = (float*)(ws + OFF_SSC);
    u64*      sup   = (u64*)(ws + OFF_SUP);
    u64*      keepm = (u64*)(ws + OFF_KEEP);
    uint32_t* flag  = (uint32_t*)(ws + OFF_FLAG);

    k_init<<<1, 64, 0, stream>>>(cnt);
    k_keys<<<(BB * NN) / 256, 256, 0, stream>>>(cls, key);
    k_select<<<BB, 256, 0, stream>>>(key, kstar);
    k_compact<<<(BB * NN) / 256, 256, 0, stream>>>(key, kstar, cnt, selk);
    k_sort<<<BB, 1024, 0, stream>>>(selk, box, sidx, ssc, bf);

    // Phase A: suppression rows [0, ROWS_A) + scan with early exit
    k_iou_t<0, ROWS_A, false><<<(ROWS_A / 4) * BB, 256, 0, stream>>>(bf, sup, flag);
    k_scan_t<0, ROWS_A><<<BB, 64, 0, stream>>>(sup, keepm, flag);
    // Phase B (per-item no-op when already finished): rows [ROWS_A, PRE)
    k_iou_t<ROWS_A, PRE, true><<<((PRE - ROWS_A) / 4) * BB, 256, 0, stream>>>(bf, sup, flag);
    k_scan_t<ROWS_A, PRE><<<BB, 64, 0, stream>>>(sup, keepm, flag);

    k_out<<<BB, 512, 0, stream>>>(keepm, sidx, ssc, box, cls, out);
}

// Round 3
// 199.727 us; speedup vs baseline: 10.3477x; 2.7257x over previous
//
#include <hip/hip_runtime.h>
#include <stdint.h>

typedef unsigned long long u64;

#define BB 4
#define NN 32768
#define CC 3
#define PRE 4096
#define POST 512
#define TH 0.7f
#define ROWS_A 768    // phase-A suppression rows (early exit expected ~576)
#define CANDCAP 4096

__device__ __forceinline__ uint32_t f2u(float f) {
    uint32_t b = __float_as_uint(f);
    return (b & 0x80000000u) ? ~b : (b | 0x80000000u);
}
__device__ __forceinline__ float u2f(uint32_t u) {
    uint32_t b = (u & 0x80000000u) ? (u & 0x7FFFFFFFu) : ~u;
    return __uint_as_float(b);
}

// 0) zero hist region (uint4 stride) + scalar counters
__global__ void k_zero(uint4* __restrict__ histreg, uint32_t* __restrict__ scal, int n16) {
    int gid = blockIdx.x * blockDim.x + threadIdx.x;
    if (gid < n16) histreg[gid] = make_uint4(0, 0, 0, 0);
    if (gid < 16) scal[gid] = 0;
}

// 1) keys + 2-level histogram of top-16 key bits.
//    key = (orderable(score)<<32) | ~index  (distinct keys => exact top_k tie-break)
__global__ void k_keys_hist(const float* __restrict__ cls, u64* __restrict__ key,
                            uint32_t* __restrict__ hist_f, uint32_t* __restrict__ hist_c) {
    __shared__ uint32_t lc[256];
    lc[threadIdx.x] = 0;
    __syncthreads();
    int gid = blockIdx.x * blockDim.x + threadIdx.x;   // 512 blocks x 256
    int b = gid >> 15;
    const float* p = cls + (size_t)gid * CC;
    float s = fmaxf(fmaxf(p[0], p[1]), p[2]);
    int n = gid & (NN - 1);
    u64 kk = ((u64)f2u(s) << 32) | (uint32_t)(~(uint32_t)n);
    key[gid] = kk;
    uint32_t p16 = (uint32_t)(kk >> 48);
    atomicAdd(&hist_f[((uint32_t)b << 16) + p16], 1u);
    atomicAdd(&lc[p16 >> 8], 1u);
    __syncthreads();
    uint32_t v = lc[threadIdx.x];
    if (v) atomicAdd(&hist_c[((uint32_t)b << 8) + threadIdx.x], v);   // block spans one item
}

// 2) choose 16-bit threshold prefix: smallest p16 with (count of keys whose top16 > p16) < PRE
//    outputs prefix16[b], kneed[b] = how many to take from the boundary bin
__global__ void k_choose(const uint32_t* __restrict__ hist_c, const uint32_t* __restrict__ hist_f,
                         uint32_t* __restrict__ prefix16, uint32_t* __restrict__ kneed) {
    int b = blockIdx.x;
    __shared__ uint32_t c[256];
    __shared__ uint32_t sel_c, rem_c;
    c[threadIdx.x] = hist_c[(b << 8) + threadIdx.x];
    __syncthreads();
    if (threadIdx.x == 0) {
        uint32_t need = PRE, cum = 0; int cc = 0;
        for (int d = 255; d >= 0; --d) {
            if (need <= cum + c[d]) { cc = d; break; }
            cum += c[d];
        }
        sel_c = (uint32_t)cc; rem_c = need - cum;
    }
    __syncthreads();
    c[threadIdx.x] = hist_f[((uint32_t)b << 16) + (sel_c << 8) + threadIdx.x];
    __syncthreads();
    if (threadIdx.x == 0) {
        uint32_t need = rem_c, cum = 0; int ff = 0;
        for (int d = 255; d >= 0; --d) {
            if (need <= cum + c[d]) { ff = d; break; }
            cum += c[d];
        }
        prefix16[b] = (sel_c << 8) | (uint32_t)ff;
        kneed[b] = need - cum;
    }
}

// 3) collect: definite winners (p16 > p*) via block-aggregated compaction (1 atomic/block),
//    boundary-bin candidates (p16 == p*) via per-thread atomic (tiny count)
__global__ void k_collect(const u64* __restrict__ key, const uint32_t* __restrict__ prefix16,
                          uint32_t* __restrict__ cnt, uint32_t* __restrict__ ccnt,
                          u64* __restrict__ selk, u64* __restrict__ cand) {
    int gid = blockIdx.x * blockDim.x + threadIdx.x;
    int b = gid >> 15;
    u64 k = key[gid];
    uint32_t p16 = (uint32_t)(k >> 48);
    uint32_t pb = prefix16[b];
    bool def = p16 > pb;
    u64 mask = __ballot(def);
    int lane = threadIdx.x & 63;
    int wave = threadIdx.x >> 6;
    __shared__ uint32_t wtot[4], wbase[4], blockbase;
    uint32_t rank = lane ? (uint32_t)__popcll(mask & ((~0ull) >> (64 - lane))) : 0u;
    if (lane == 0) wtot[wave] = (uint32_t)__popcll(mask);
    __syncthreads();
    if (threadIdx.x == 0) {
        uint32_t t = 0;
        for (int w = 0; w < 4; ++w) { wbase[w] = t; t += wtot[w]; }
        blockbase = atomicAdd(&cnt[b], t);
    }
    __syncthreads();
    if (def) {
        selk[(size_t)b * PRE + blockbase + wbase[wave] + rank] = k;
    } else if (p16 == pb) {
        uint32_t pos = atomicAdd(&ccnt[b], 1u);
        if (pos < CANDCAP) cand[(size_t)b * CANDCAP + pos] = k;
    }
}

// 4) sort boundary candidates (bitonic, runtime pow2 <= CANDCAP), append top kneed to selk
__global__ void __launch_bounds__(256) k_final(const u64* __restrict__ cand,
                                               const uint32_t* __restrict__ ccnt,
                                               const uint32_t* __restrict__ kneed,
                                               const uint32_t* __restrict__ cnt,
                                               u64* __restrict__ selk) {
    int b = blockIdx.x;
    __shared__ u64 s[CANDCAP];
    uint32_t n = ccnt[b];
    if (n > CANDCAP) n = CANDCAP;
    uint32_t kn = kneed[b];
    uint32_t m = 64;
    while (m < n) m <<= 1;
    for (uint32_t i = threadIdx.x; i < m; i += blockDim.x)
        s[i] = (i < n) ? cand[(size_t)b * CANDCAP + i] : 0ull;
    __syncthreads();
    for (uint32_t k = 2; k <= m; k <<= 1) {
        for (uint32_t j = k >> 1; j > 0; j >>= 1) {
            for (uint32_t i = threadIdx.x; i < m; i += blockDim.x) {
                uint32_t ixj = i ^ j;
                if (ixj > i) {
                    u64 a = s[i], c2 = s[ixj];
                    bool desc = ((i & k) == 0);
                    if (desc ? (a < c2) : (a > c2)) { s[i] = c2; s[ixj] = a; }
                }
            }
            __syncthreads();
        }
    }
    uint32_t base = cnt[b];   // == PRE - kn
    for (uint32_t i = threadIdx.x; i < kn; i += blockDim.x)
        selk[(size_t)b * PRE + base + i] = s[i];
}

// 5) bitonic sort (descending) of 4096 keys in LDS; derive orig idx, score, box features
__global__ void __launch_bounds__(1024) k_sort(const u64* __restrict__ selk,
                                               const float* __restrict__ box,
                                               int* __restrict__ sidx, float* __restrict__ ssc,
                                               float* __restrict__ bf) {
    int b = blockIdx.x;
    __shared__ u64 s[PRE];
    const u64* sk = selk + (size_t)b * PRE;
    for (int i = threadIdx.x; i < PRE; i += blockDim.x) s[i] = sk[i];
    __syncthreads();
    for (int k = 2; k <= PRE; k <<= 1) {
        for (int j = k >> 1; j > 0; j >>= 1) {
            for (int i = threadIdx.x; i < PRE; i += blockDim.x) {
                int ixj = i ^ j;
                if (ixj > i) {
                    u64 a = s[i], c = s[ixj];
                    bool desc = ((i & k) == 0);
                    if (desc ? (a < c) : (a > c)) { s[i] = c; s[ixj] = a; }
                }
            }
            __syncthreads();
        }
    }
    float* bfb = bf + (size_t)b * 5 * PRE;
    for (int r = threadIdx.x; r < PRE; r += blockDim.x) {
        u64 kk = s[r];
        int n = (int)(~(uint32_t)(kk & 0xFFFFFFFFull));
        float sc = u2f((uint32_t)(kk >> 32));
        sidx[b * PRE + r] = n;
        ssc[b * PRE + r] = sc;
        const float* bp = box + ((size_t)b * NN + n) * 7;
        float x = bp[0], y = bp[1], dx = bp[3], dy = bp[4];
        bfb[0 * PRE + r] = x - dx * 0.5f;
        bfb[1 * PRE + r] = x + dx * 0.5f;
        bfb[2 * PRE + r] = y - dy * 0.5f;
        bfb[3 * PRE + r] = y + dy * 0.5f;
        bfb[4 * PRE + r] = dx * dy;
    }
}

// 6) suppression rows [START,END): one wave per row i, lane = column within 64-wide group
template<int START, int END, bool CHECK_FLAG>
__global__ void k_iou_t(const float* __restrict__ bf, u64* __restrict__ sup,
                        const uint32_t* __restrict__ flag) {
    const int bpi = (END - START) / 4;       // blocks per item (4 waves/block)
    int b = blockIdx.x / bpi;
    if (CHECK_FLAG && flag[b]) return;
    int wave = threadIdx.x >> 6;
    int lane = threadIdx.x & 63;
    int i = START + (blockIdx.x % bpi) * 4 + wave;
    const float* bfb = bf + (size_t)b * 5 * PRE;
    float x1 = bfb[0 * PRE + i], x2 = bfb[1 * PRE + i];
    float y1 = bfb[2 * PRE + i], y2 = bfb[3 * PRE + i];
    float ar = bfb[4 * PRE + i];
    u64 myword = 0;
    for (int jw = 0; jw < 64; ++jw) {
        int j = jw * 64 + lane;
        float jx1 = bfb[0 * PRE + j], jx2 = bfb[1 * PRE + j];
        float jy1 = bfb[2 * PRE + j], jy2 = bfb[3 * PRE + j];
        float jar = bfb[4 * PRE + j];
        float ix = fminf(x2, jx2) - fmaxf(x1, jx1);
        ix = fmaxf(ix, 0.0f);
        float iy = fminf(y2, jy2) - fmaxf(y1, jy1);
        iy = fmaxf(iy, 0.0f);
        float inter = __fmul_rn(ix, iy);            // block FMA contraction (match np rounding)
        float uni = (ar + jar) - inter;
        float iou = inter / fmaxf(uni, 1e-6f);
        u64 bal = __ballot((iou > TH) && (j > i));
        if (jw == lane) myword = bal;
    }
    sup[((size_t)b * PRE + i) * 64 + lane] = myword;
}

__device__ __forceinline__ uint32_t kept_count(u64 removed, int words, int lane) {
    int v = (lane < words) ? __popcll(~removed) : 0;
#pragma unroll
    for (int off = 32; off > 0; off >>= 1) v += __shfl_xor(v, off, 64);
    return (uint32_t)v;
}

// 7) greedy scan rows [START,END): 1 wave/item, lane w owns removed-word w.
//    32-row double-buffered register chunks; early exit once POST kept rows finalized.
template<int START, int END>
__global__ void k_scan_t(const u64* __restrict__ sup, u64* __restrict__ keepm,
                         uint32_t* __restrict__ flag) {
    const int CH = 32;
    int b = blockIdx.x;
    int lane = threadIdx.x;   // 64 threads = 1 wave
    if (START > 0) { if (flag[b]) return; }
    u64 removed = (START > 0) ? keepm[b * 64 + lane] : 0ull;
    const u64* sb = sup + (size_t)b * PRE * 64;

    u64 bufA[CH], bufB[CH];
#pragma unroll
    for (int p = 0; p < CH; ++p) bufA[p] = sb[(size_t)(START + p) * 64 + lane];

    bool fin = false;
    int S = END;
    for (int g = START; g < END; g += 64) {
#pragma unroll
        for (int p = 0; p < CH; ++p) bufB[p] = sb[(size_t)(g + CH + p) * 64 + lane];
#pragma unroll
        for (int p = 0; p < CH; ++p) {
            int i = g + p;
            u64 rw = __shfl(removed, i >> 6, 64);
            if (!((rw >> (i & 63)) & 1ull)) removed |= bufA[p];
        }
        if (g + 64 < END) {
#pragma unroll
            for (int p = 0; p < CH; ++p) bufA[p] = sb[(size_t)(g + 64 + p) * 64 + lane];
        }
#pragma unroll
        for (int p = 0; p < CH; ++p) {
            int i = g + CH + p;
            u64 rw = __shfl(removed, i >> 6, 64);
            if (!((rw >> (i & 63)) & 1ull)) removed |= bufB[p];
        }
        uint32_t kept = kept_count(removed, (g + 64) >> 6, lane);
        if (kept >= POST) { S = g + 64; fin = true; break; }
    }

    if (!fin && END < PRE) {
        keepm[b * 64 + lane] = removed;
        if (lane == 0) flag[b] = 0;
    } else {
        int words = S >> 6;
        keepm[b * 64 + lane] = (lane < words) ? ~removed : 0ull;
        if (lane == 0) flag[b] = 1;
    }
}

// 8) outputs: destination = position in argsort(where(keep, rank, PRE))
__global__ void __launch_bounds__(512) k_out(const u64* __restrict__ keepm,
                                             const int* __restrict__ sidx,
                                             const float* __restrict__ ssc,
                                             const float* __restrict__ box,
                                             const float* __restrict__ cls,
                                             float* __restrict__ out) {
    int b = blockIdx.x;
    __shared__ uint32_t wpre[65];
    const u64* km = keepm + b * 64;
    if (threadIdx.x == 0) {
        uint32_t c = 0;
        for (int w = 0; w < 64; ++w) { wpre[w] = c; c += (uint32_t)__popcll(km[w]); }
        wpre[64] = c;
    }
    __syncthreads();
    uint32_t nkeep = wpre[64];
    for (int r = threadIdx.x; r < PRE; r += blockDim.x) {
        int w = r >> 6, bit = r & 63;
        u64 word = km[w];
        bool kept = (word >> bit) & 1ull;
        u64 mask = bit ? ((1ull << bit) - 1ull) : 0ull;
        uint32_t before = wpre[w] + (uint32_t)__popcll(word & mask);
        uint32_t d = kept ? before : (nkeep + (uint32_t)r - before);
        if (d < POST) {
            float* ro = out + ((size_t)b * POST + d) * 7;
            float* so = out + (size_t)BB * POST * 7 + b * POST + d;
            float* lo = out + (size_t)BB * POST * 8 + b * POST + d;
            if (kept) {
                int n = sidx[b * PRE + r];
                const float* bp = box + ((size_t)b * NN + n) * 7;
#pragma unroll
                for (int t = 0; t < 7; ++t) ro[t] = bp[t];
                *so = ssc[b * PRE + r];
                const float* cp = cls + ((size_t)b * NN + n) * CC;
                float c0 = cp[0], c1 = cp[1], c2 = cp[2];
                int lbl = 0; float bst = c0;
                if (c1 > bst) { bst = c1; lbl = 1; }
                if (c2 > bst) { lbl = 2; }
                *lo = (float)(lbl + 1);
            } else {
#pragma unroll
                for (int t = 0; t < 7; ++t) ro[t] = 0.0f;
                *so = 0.0f;
                *lo = 1.0f;
            }
        }
    }
}

extern "C" void kernel_launch(void* const* d_in, const int* in_sizes, int n_in,
                              void* d_out, int out_size, void* d_ws, size_t ws_size,
                              hipStream_t stream) {
    const float* cls = (const float*)d_in[0];   // (4, 32768, 3)
    const float* box = (const float*)d_in[1];   // (4, 32768, 7)
    float* out = (float*)d_out;                 // 18432 floats

    char* ws = (char*)d_ws;
    const size_t MB = 1024 * 1024;
    // sup occupies [0, 8MB); key/hists/cand/selk alias inside it (all dead before k_iou writes)
    size_t OFF_SUP   = 0;
    size_t OFF_KEY   = 0;                        // 1 MB
    size_t OFF_HISTF = 1 * MB;                   // 1 MB  (4 x 65536 x 4)
    size_t OFF_HISTC = 2 * MB;                   // 4 KB  (4 x 256 x 4)
    size_t OFF_CAND  = 2 * MB + 4096;            // 128 KB (4 x 4096 x 8)
    size_t OFF_SELK  = 3 * MB;                   // 128 KB
    size_t OFF_BF    = 8 * MB;                   // 320 KB
    size_t OFF_SIDX  = OFF_BF + (size_t)BB * 5 * PRE * 4;
    size_t OFF_SSC   = OFF_SIDX + (size_t)BB * PRE * 4;
    size_t OFF_KEEP  = OFF_SSC + (size_t)BB * PRE * 4;
    size_t OFF_SCAL  = OFF_KEEP + (size_t)BB * 64 * 8;   // cnt[4],ccnt[4],flag[4],pad
    size_t OFF_PFX   = OFF_SCAL + 64;                    // prefix16[4], kneed[4]

    u64*      sup    = (u64*)(ws + OFF_SUP);
    u64*      key    = (u64*)(ws + OFF_KEY);
    uint32_t* hist_f = (uint32_t*)(ws + OFF_HISTF);
    uint32_t* hist_c = (uint32_t*)(ws + OFF_HISTC);
    u64*      cand   = (u64*)(ws + OFF_CAND);
    u64*      selk   = (u64*)(ws + OFF_SELK);
    float*    bf     = (float*)(ws + OFF_BF);
    int*      sidx   = (int*)(ws + OFF_SIDX);
    float*    ssc    = (float*)(ws + OFF_SSC);
    u64*      keepm  = (u64*)(ws + OFF_KEEP);
    uint32_t* scal   = (uint32_t*)(ws + OFF_SCAL);
    uint32_t* cnt    = scal;
    uint32_t* ccnt   = scal + 4;
    uint32_t* flag   = scal + 8;
    uint32_t* prefix16 = (uint32_t*)(ws + OFF_PFX);
    uint32_t* kneed  = prefix16 + 4;

    // zero hist_f + hist_c (contiguous 1MB+4KB) and counters
    int n16 = (int)((MB + 4096) / 16);
    k_zero<<<(n16 + 255) / 256, 256, 0, stream>>>((uint4*)(ws + OFF_HISTF), scal, n16);
    k_keys_hist<<<(BB * NN) / 256, 256, 0, stream>>>(cls, key, hist_f, hist_c);
    k_choose<<<BB, 256, 0, stream>>>(hist_c, hist_f, prefix16, kneed);
    k_collect<<<(BB * NN) / 256, 256, 0, stream>>>(key, prefix16, cnt, ccnt, selk, cand);
    k_final<<<BB, 256, 0, stream>>>(cand, ccnt, kneed, cnt, selk);
    k_sort<<<BB, 1024, 0, stream>>>(selk, box, sidx, ssc, bf);

    // Phase A: suppression rows [0, ROWS_A) + scan with early exit
    k_iou_t<0, ROWS_A, false><<<(ROWS_A / 4) * BB, 256, 0, stream>>>(bf, sup, flag);
    k_scan_t<0, ROWS_A><<<BB, 64, 0, stream>>>(sup, keepm, flag);
    // Phase B (per-item no-op when already finished): rows [ROWS_A, PRE)
    k_iou_t<ROWS_A, PRE, true><<<((PRE - ROWS_A) / 4) * BB, 256, 0, stream>>>(bf, sup, flag);
    k_scan_t<ROWS_A, PRE><<<BB, 64, 0, stream>>>(sup, keepm, flag);

    k_out<<<BB, 512, 0, stream>>>(keepm, sidx, ssc, box, cls, out);
}

// Round 4
// 181.259 us; speedup vs baseline: 11.4021x; 1.1019x over previous
//
#include <hip/hip_runtime.h>
#include <stdint.h>

typedef unsigned long long u64;

#define BB 4
#define NN 32768
#define CC 3
#define PRE 4096
#define POST 512
#define TH 0.7f
#define ROWS_A 768    // phase-A suppression rows (early exit expected ~576)
#define CANDCAP 4096
#define RANK_BPI 16   // rank blocks per item

__device__ __forceinline__ uint32_t f2u(float f) {
    uint32_t b = __float_as_uint(f);
    return (b & 0x80000000u) ? ~b : (b | 0x80000000u);
}
__device__ __forceinline__ float u2f(uint32_t u) {
    uint32_t b = (u & 0x80000000u) ? (u & 0x7FFFFFFFu) : ~u;
    return __uint_as_float(b);
}

// 0) zero hist region (uint4 stride) + scalar counters
__global__ void k_zero(uint4* __restrict__ histreg, uint32_t* __restrict__ scal, int n16) {
    int gid = blockIdx.x * blockDim.x + threadIdx.x;
    if (gid < n16) histreg[gid] = make_uint4(0, 0, 0, 0);
    if (gid < 16) scal[gid] = 0;
}

// 1) keys + 2-level histogram of top-16 key bits.
//    key = (orderable(score)<<32) | ~index  (distinct keys => exact top_k tie-break)
__global__ void k_keys_hist(const float* __restrict__ cls, u64* __restrict__ key,
                            uint32_t* __restrict__ hist_f, uint32_t* __restrict__ hist_c) {
    __shared__ uint32_t lc[256];
    lc[threadIdx.x] = 0;
    __syncthreads();
    int gid = blockIdx.x * blockDim.x + threadIdx.x;   // 512 blocks x 256
    int b = gid >> 15;
    const float* p = cls + (size_t)gid * CC;
    float s = fmaxf(fmaxf(p[0], p[1]), p[2]);
    int n = gid & (NN - 1);
    u64 kk = ((u64)f2u(s) << 32) | (uint32_t)(~(uint32_t)n);
    key[gid] = kk;
    uint32_t p16 = (uint32_t)(kk >> 48);
    atomicAdd(&hist_f[((uint32_t)b << 16) + p16], 1u);
    atomicAdd(&lc[p16 >> 8], 1u);
    __syncthreads();
    uint32_t v = lc[threadIdx.x];
    if (v) atomicAdd(&hist_c[((uint32_t)b << 8) + threadIdx.x], v);   // block spans one item
}

// 2) choose 16-bit threshold prefix: smallest p16 with (count of keys whose top16 > p16) < PRE
__global__ void k_choose(const uint32_t* __restrict__ hist_c, const uint32_t* __restrict__ hist_f,
                         uint32_t* __restrict__ prefix16, uint32_t* __restrict__ kneed) {
    int b = blockIdx.x;
    __shared__ uint32_t c[256];
    __shared__ uint32_t sel_c, rem_c;
    c[threadIdx.x] = hist_c[(b << 8) + threadIdx.x];
    __syncthreads();
    if (threadIdx.x == 0) {
        uint32_t need = PRE, cum = 0; int cc = 0;
        for (int d = 255; d >= 0; --d) {
            if (need <= cum + c[d]) { cc = d; break; }
            cum += c[d];
        }
        sel_c = (uint32_t)cc; rem_c = need - cum;
    }
    __syncthreads();
    c[threadIdx.x] = hist_f[((uint32_t)b << 16) + (sel_c << 8) + threadIdx.x];
    __syncthreads();
    if (threadIdx.x == 0) {
        uint32_t need = rem_c, cum = 0; int ff = 0;
        for (int d = 255; d >= 0; --d) {
            if (need <= cum + c[d]) { ff = d; break; }
            cum += c[d];
        }
        prefix16[b] = (sel_c << 8) | (uint32_t)ff;
        kneed[b] = need - cum;
    }
}

// 3) collect: definite winners (p16 > p*) via block-aggregated compaction (1 atomic/block),
//    boundary-bin candidates (p16 == p*) via per-thread atomic (tiny count)
__global__ void k_collect(const u64* __restrict__ key, const uint32_t* __restrict__ prefix16,
                          uint32_t* __restrict__ cnt, uint32_t* __restrict__ ccnt,
                          u64* __restrict__ selk, u64* __restrict__ cand) {
    int gid = blockIdx.x * blockDim.x + threadIdx.x;
    int b = gid >> 15;
    u64 k = key[gid];
    uint32_t p16 = (uint32_t)(k >> 48);
    uint32_t pb = prefix16[b];
    bool def = p16 > pb;
    u64 mask = __ballot(def);
    int lane = threadIdx.x & 63;
    int wave = threadIdx.x >> 6;
    __shared__ uint32_t wtot[4], wbase[4], blockbase;
    uint32_t rank = lane ? (uint32_t)__popcll(mask & ((~0ull) >> (64 - lane))) : 0u;
    if (lane == 0) wtot[wave] = (uint32_t)__popcll(mask);
    __syncthreads();
    if (threadIdx.x == 0) {
        uint32_t t = 0;
        for (int w = 0; w < 4; ++w) { wbase[w] = t; t += wtot[w]; }
        blockbase = atomicAdd(&cnt[b], t);
    }
    __syncthreads();
    if (def) {
        selk[(size_t)b * PRE + blockbase + wbase[wave] + rank] = k;
    } else if (p16 == pb) {
        uint32_t pos = atomicAdd(&ccnt[b], 1u);
        if (pos < CANDCAP) cand[(size_t)b * CANDCAP + pos] = k;
    }
}

// 4) sort boundary candidates (bitonic, runtime pow2 <= CANDCAP), append top kneed to selk
__global__ void __launch_bounds__(256) k_final(const u64* __restrict__ cand,
                                               const uint32_t* __restrict__ ccnt,
                                               const uint32_t* __restrict__ kneed,
                                               const uint32_t* __restrict__ cnt,
                                               u64* __restrict__ selk) {
    int b = blockIdx.x;
    __shared__ u64 s[CANDCAP];
    uint32_t n = ccnt[b];
    if (n > CANDCAP) n = CANDCAP;
    uint32_t kn = kneed[b];
    uint32_t m = 64;
    while (m < n) m <<= 1;
    for (uint32_t i = threadIdx.x; i < m; i += blockDim.x)
        s[i] = (i < n) ? cand[(size_t)b * CANDCAP + i] : 0ull;
    __syncthreads();
    for (uint32_t k = 2; k <= m; k <<= 1) {
        for (uint32_t j = k >> 1; j > 0; j >>= 1) {
            for (uint32_t i = threadIdx.x; i < m; i += blockDim.x) {
                uint32_t ixj = i ^ j;
                if (ixj > i) {
                    u64 a = s[i], c2 = s[ixj];
                    bool desc = ((i & k) == 0);
                    if (desc ? (a < c2) : (a > c2)) { s[i] = c2; s[ixj] = a; }
                }
            }
            __syncthreads();
        }
    }
    uint32_t base = cnt[b];   // == PRE - kn
    for (uint32_t i = threadIdx.x; i < kn; i += blockDim.x)
        selk[(size_t)b * PRE + base + i] = s[i];
}

// 5) counting rank (replaces bitonic sort): keys distinct => rank(k) = #{k' > k}.
//    16 blocks/item x 256 threads; 1024-key LDS tiles, same-address broadcast reads.
//    Each thread scatters idx/score/box-features at its exact rank.
__global__ void __launch_bounds__(256) k_rank(const u64* __restrict__ selk,
                                              const float* __restrict__ box,
                                              int* __restrict__ sidx, float* __restrict__ ssc,
                                              float* __restrict__ bf) {
    int b = blockIdx.x / RANK_BPI;
    int c = blockIdx.x % RANK_BPI;
    const u64* sk = selk + (size_t)b * PRE;
    u64 myk = sk[c * 256 + threadIdx.x];
    __shared__ u64 tile[1024];
    int cnt = 0;
    for (int t0 = 0; t0 < PRE; t0 += 1024) {
        for (int i = threadIdx.x; i < 1024; i += 256) tile[i] = sk[t0 + i];
        __syncthreads();
#pragma unroll 16
        for (int j = 0; j < 1024; ++j) cnt += (tile[j] > myk) ? 1 : 0;
        __syncthreads();
    }
    int r = cnt;   // descending rank, exact (keys distinct)
    int n = (int)(~(uint32_t)(myk & 0xFFFFFFFFull));
    float sc = u2f((uint32_t)(myk >> 32));
    sidx[b * PRE + r] = n;
    ssc[b * PRE + r] = sc;
    const float* bp = box + ((size_t)b * NN + n) * 7;
    float x = bp[0], y = bp[1], dx = bp[3], dy = bp[4];
    float* bfb = bf + (size_t)b * 5 * PRE;
    bfb[0 * PRE + r] = x - dx * 0.5f;
    bfb[1 * PRE + r] = x + dx * 0.5f;
    bfb[2 * PRE + r] = y - dy * 0.5f;
    bfb[3 * PRE + r] = y + dy * 0.5f;
    bfb[4 * PRE + r] = dx * dy;
}

// 6) suppression rows [START,END): one wave per row i, lane = column within 64-wide group
template<int START, int END, bool CHECK_FLAG>
__global__ void k_iou_t(const float* __restrict__ bf, u64* __restrict__ sup,
                        const uint32_t* __restrict__ flag) {
    const int bpi = (END - START) / 4;       // blocks per item (4 waves/block)
    int b = blockIdx.x / bpi;
    if (CHECK_FLAG && flag[b]) return;
    int wave = threadIdx.x >> 6;
    int lane = threadIdx.x & 63;
    int i = START + (blockIdx.x % bpi) * 4 + wave;
    const float* bfb = bf + (size_t)b * 5 * PRE;
    float x1 = bfb[0 * PRE + i], x2 = bfb[1 * PRE + i];
    float y1 = bfb[2 * PRE + i], y2 = bfb[3 * PRE + i];
    float ar = bfb[4 * PRE + i];
    u64 myword = 0;
    for (int jw = 0; jw < 64; ++jw) {
        int j = jw * 64 + lane;
        float jx1 = bfb[0 * PRE + j], jx2 = bfb[1 * PRE + j];
        float jy1 = bfb[2 * PRE + j], jy2 = bfb[3 * PRE + j];
        float jar = bfb[4 * PRE + j];
        float ix = fminf(x2, jx2) - fmaxf(x1, jx1);
        ix = fmaxf(ix, 0.0f);
        float iy = fminf(y2, jy2) - fmaxf(y1, jy1);
        iy = fmaxf(iy, 0.0f);
        float inter = __fmul_rn(ix, iy);            // block FMA contraction (match np rounding)
        float uni = (ar + jar) - inter;
        float iou = inter / fmaxf(uni, 1e-6f);
        u64 bal = __ballot((iou > TH) && (j > i));
        if (jw == lane) myword = bal;
    }
    sup[((size_t)b * PRE + i) * 64 + lane] = myword;
}

__device__ __forceinline__ uint32_t kept_count(u64 removed, int words, int lane) {
    int v = (lane < words) ? __popcll(~removed) : 0;
#pragma unroll
    for (int off = 32; off > 0; off >>= 1) v += __shfl_xor(v, off, 64);
    return (uint32_t)v;
}

// 7) greedy scan rows [START,END): 1 wave/item, lane w owns removed-word w.
//    32-row double-buffered register chunks; early exit once POST kept rows finalized.
template<int START, int END>
__global__ void k_scan_t(const u64* __restrict__ sup, u64* __restrict__ keepm,
                         uint32_t* __restrict__ flag) {
    const int CH = 32;
    int b = blockIdx.x;
    int lane = threadIdx.x;   // 64 threads = 1 wave
    if (START > 0) { if (flag[b]) return; }
    u64 removed = (START > 0) ? keepm[b * 64 + lane] : 0ull;
    const u64* sb = sup + (size_t)b * PRE * 64;

    u64 bufA[CH], bufB[CH];
#pragma unroll
    for (int p = 0; p < CH; ++p) bufA[p] = sb[(size_t)(START + p) * 64 + lane];

    bool fin = false;
    int S = END;
    for (int g = START; g < END; g += 64) {
#pragma unroll
        for (int p = 0; p < CH; ++p) bufB[p] = sb[(size_t)(g + CH + p) * 64 + lane];
#pragma unroll
        for (int p = 0; p < CH; ++p) {
            int i = g + p;
            u64 rw = __shfl(removed, i >> 6, 64);
            if (!((rw >> (i & 63)) & 1ull)) removed |= bufA[p];
        }
        if (g + 64 < END) {
#pragma unroll
            for (int p = 0; p < CH; ++p) bufA[p] = sb[(size_t)(g + 64 + p) * 64 + lane];
        }
#pragma unroll
        for (int p = 0; p < CH; ++p) {
            int i = g + CH + p;
            u64 rw = __shfl(removed, i >> 6, 64);
            if (!((rw >> (i & 63)) & 1ull)) removed |= bufB[p];
        }
        uint32_t kept = kept_count(removed, (g + 64) >> 6, lane);
        if (kept >= POST) { S = g + 64; fin = true; break; }
    }

    if (!fin && END < PRE) {
        keepm[b * 64 + lane] = removed;
        if (lane == 0) flag[b] = 0;
    } else {
        int words = S >> 6;
        keepm[b * 64 + lane] = (lane < words) ? ~removed : 0ull;
        if (lane == 0) flag[b] = 1;
    }
}

// 8) outputs: destination = position in argsort(where(keep, rank, PRE))
__global__ void __launch_bounds__(512) k_out(const u64* __restrict__ keepm,
                                             const int* __restrict__ sidx,
                                             const float* __restrict__ ssc,
                                             const float* __restrict__ box,
                                             const float* __restrict__ cls,
                                             float* __restrict__ out) {
    int b = blockIdx.x;
    __shared__ uint32_t wpre[65];
    const u64* km = keepm + b * 64;
    if (threadIdx.x == 0) {
        uint32_t c = 0;
        for (int w = 0; w < 64; ++w) { wpre[w] = c; c += (uint32_t)__popcll(km[w]); }
        wpre[64] = c;
    }
    __syncthreads();
    uint32_t nkeep = wpre[64];
    for (int r = threadIdx.x; r < PRE; r += blockDim.x) {
        int w = r >> 6, bit = r & 63;
        u64 word = km[w];
        bool kept = (word >> bit) & 1ull;
        u64 mask = bit ? ((1ull << bit) - 1ull) : 0ull;
        uint32_t before = wpre[w] + (uint32_t)__popcll(word & mask);
        uint32_t d = kept ? before : (nkeep + (uint32_t)r - before);
        if (d < POST) {
            float* ro = out + ((size_t)b * POST + d) * 7;
            float* so = out + (size_t)BB * POST * 7 + b * POST + d;
            float* lo = out + (size_t)BB * POST * 8 + b * POST + d;
            if (kept) {
                int n = sidx[b * PRE + r];
                const float* bp = box + ((size_t)b * NN + n) * 7;
#pragma unroll
                for (int t = 0; t < 7; ++t) ro[t] = bp[t];
                *so = ssc[b * PRE + r];
                const float* cp = cls + ((size_t)b * NN + n) * CC;
                float c0 = cp[0], c1 = cp[1], c2 = cp[2];
                int lbl = 0; float bst = c0;
                if (c1 > bst) { bst = c1; lbl = 1; }
                if (c2 > bst) { lbl = 2; }
                *lo = (float)(lbl + 1);
            } else {
#pragma unroll
                for (int t = 0; t < 7; ++t) ro[t] = 0.0f;
                *so = 0.0f;
                *lo = 1.0f;
            }
        }
    }
}

extern "C" void kernel_launch(void* const* d_in, const int* in_sizes, int n_in,
                              void* d_out, int out_size, void* d_ws, size_t ws_size,
                              hipStream_t stream) {
    const float* cls = (const float*)d_in[0];   // (4, 32768, 3)
    const float* box = (const float*)d_in[1];   // (4, 32768, 7)
    float* out = (float*)d_out;                 // 18432 floats

    char* ws = (char*)d_ws;
    const size_t MB = 1024 * 1024;
    // sup occupies [0, 8MB); key/hists/cand/selk alias inside it (all dead before k_iou writes)
    size_t OFF_SUP   = 0;
    size_t OFF_KEY   = 0;                        // 1 MB
    size_t OFF_HISTF = 1 * MB;                   // 1 MB  (4 x 65536 x 4)
    size_t OFF_HISTC = 2 * MB;                   // 4 KB  (4 x 256 x 4)
    size_t OFF_CAND  = 2 * MB + 4096;            // 128 KB (4 x 4096 x 8)
    size_t OFF_SELK  = 3 * MB;                   // 128 KB
    size_t OFF_BF    = 8 * MB;                   // 320 KB
    size_t OFF_SIDX  = OFF_BF + (size_t)BB * 5 * PRE * 4;
    size_t OFF_SSC   = OFF_SIDX + (size_t)BB * PRE * 4;
    size_t OFF_KEEP  = OFF_SSC + (size_t)BB * PRE * 4;
    size_t OFF_SCAL  = OFF_KEEP + (size_t)BB * 64 * 8;   // cnt[4],ccnt[4],flag[4],pad
    size_t OFF_PFX   = OFF_SCAL + 64;                    // prefix16[4], kneed[4]

    u64*      sup    = (u64*)(ws + OFF_SUP);
    u64*      key    = (u64*)(ws + OFF_KEY);
    uint32_t* hist_f = (uint32_t*)(ws + OFF_HISTF);
    uint32_t* hist_c = (uint32_t*)(ws + OFF_HISTC);
    u64*      cand   = (u64*)(ws + OFF_CAND);
    u64*      selk   = (u64*)(ws + OFF_SELK);
    float*    bf     = (float*)(ws + OFF_BF);
    int*      sidx   = (int*)(ws + OFF_SIDX);
    float*    ssc    = (float*)(ws + OFF_SSC);
    u64*      keepm  = (u64*)(ws + OFF_KEEP);
    uint32_t* scal   = (uint32_t*)(ws + OFF_SCAL);
    uint32_t* cnt    = scal;
    uint32_t* ccnt   = scal + 4;
    uint32_t* flag   = scal + 8;
    uint32_t* prefix16 = (uint32_t*)(ws + OFF_PFX);
    uint32_t* kneed  = prefix16 + 4;

    // zero hist_f + hist_c (contiguous 1MB+4KB) and counters
    int n16 = (int)((MB + 4096) / 16);
    k_zero<<<(n16 + 255) / 256, 256, 0, stream>>>((uint4*)(ws + OFF_HISTF), scal, n16);
    k_keys_hist<<<(BB * NN) / 256, 256, 0, stream>>>(cls, key, hist_f, hist_c);
    k_choose<<<BB, 256, 0, stream>>>(hist_c, hist_f, prefix16, kneed);
    k_collect<<<(BB * NN) / 256, 256, 0, stream>>>(key, prefix16, cnt, ccnt, selk, cand);
    k_final<<<BB, 256, 0, stream>>>(cand, ccnt, kneed, cnt, selk);
    k_rank<<<BB * RANK_BPI, 256, 0, stream>>>(selk, box, sidx, ssc, bf);

    // Phase A: suppression rows [0, ROWS_A) + scan with early exit
    k_iou_t<0, ROWS_A, false><<<(ROWS_A / 4) * BB, 256, 0, stream>>>(bf, sup, flag);
    k_scan_t<0, ROWS_A><<<BB, 64, 0, stream>>>(sup, keepm, flag);
    // Phase B (per-item no-op when already finished): rows [ROWS_A, PRE)
    k_iou_t<ROWS_A, PRE, true><<<((PRE - ROWS_A) / 4) * BB, 256, 0, stream>>>(bf, sup, flag);
    k_scan_t<ROWS_A, PRE><<<BB, 64, 0, stream>>>(sup, keepm, flag);

    k_out<<<BB, 512, 0, stream>>>(keepm, sidx, ssc, box, cls, out);
}

// Round 5
// 171.506 us; speedup vs baseline: 12.0505x; 1.0569x over previous
//
#include <hip/hip_runtime.h>
#include <stdint.h>

typedef unsigned long long u64;

#define BB 4
#define NN 32768
#define CC 3
#define PRE 4096
#define POST 512
#define TH 0.7f
#define ROWS_A 768    // phase-A rows AND cols (12 words); early exit expected ~576-640
#define CANDCAP 4096
#define RANK_BPI 16   // rank blocks per item

__device__ __forceinline__ uint32_t f2u(float f) {
    uint32_t b = __float_as_uint(f);
    return (b & 0x80000000u) ? ~b : (b | 0x80000000u);
}
__device__ __forceinline__ float u2f(uint32_t u) {
    uint32_t b = (u & 0x80000000u) ? (u & 0x7FFFFFFFu) : ~u;
    return __uint_as_float(b);
}

// 0) zero hist region (uint4 stride) + scalar counters
__global__ void k_zero(uint4* __restrict__ histreg, uint32_t* __restrict__ scal, int n16) {
    int gid = blockIdx.x * blockDim.x + threadIdx.x;
    if (gid < n16) histreg[gid] = make_uint4(0, 0, 0, 0);
    if (gid < 16) scal[gid] = 0;
}

// 1) keys + 2-level histogram of top-16 key bits.
//    key = (orderable(score)<<32) | ~index  (distinct keys => exact top_k tie-break)
__global__ void k_keys_hist(const float* __restrict__ cls, u64* __restrict__ key,
                            uint32_t* __restrict__ hist_f, uint32_t* __restrict__ hist_c) {
    __shared__ uint32_t lc[256];
    lc[threadIdx.x] = 0;
    __syncthreads();
    int gid = blockIdx.x * blockDim.x + threadIdx.x;   // 512 blocks x 256
    int b = gid >> 15;
    const float* p = cls + (size_t)gid * CC;
    float s = fmaxf(fmaxf(p[0], p[1]), p[2]);
    int n = gid & (NN - 1);
    u64 kk = ((u64)f2u(s) << 32) | (uint32_t)(~(uint32_t)n);
    key[gid] = kk;
    uint32_t p16 = (uint32_t)(kk >> 48);
    atomicAdd(&hist_f[((uint32_t)b << 16) + p16], 1u);
    atomicAdd(&lc[p16 >> 8], 1u);
    __syncthreads();
    uint32_t v = lc[threadIdx.x];
    if (v) atomicAdd(&hist_c[((uint32_t)b << 8) + threadIdx.x], v);   // block spans one item
}

// 2) choose 16-bit threshold prefix: smallest p16 with (count of keys whose top16 > p16) < PRE
__global__ void k_choose(const uint32_t* __restrict__ hist_c, const uint32_t* __restrict__ hist_f,
                         uint32_t* __restrict__ prefix16, uint32_t* __restrict__ kneed) {
    int b = blockIdx.x;
    __shared__ uint32_t c[256];
    __shared__ uint32_t sel_c, rem_c;
    c[threadIdx.x] = hist_c[(b << 8) + threadIdx.x];
    __syncthreads();
    if (threadIdx.x == 0) {
        uint32_t need = PRE, cum = 0; int cc = 0;
        for (int d = 255; d >= 0; --d) {
            if (need <= cum + c[d]) { cc = d; break; }
            cum += c[d];
        }
        sel_c = (uint32_t)cc; rem_c = need - cum;
    }
    __syncthreads();
    c[threadIdx.x] = hist_f[((uint32_t)b << 16) + (sel_c << 8) + threadIdx.x];
    __syncthreads();
    if (threadIdx.x == 0) {
        uint32_t need = rem_c, cum = 0; int ff = 0;
        for (int d = 255; d >= 0; --d) {
            if (need <= cum + c[d]) { ff = d; break; }
            cum += c[d];
        }
        prefix16[b] = (sel_c << 8) | (uint32_t)ff;
        kneed[b] = need - cum;
    }
}

// 3) collect: definite winners (p16 > p*) via block-aggregated compaction (1 atomic/block),
//    boundary-bin candidates (p16 == p*) via per-thread atomic (tiny count)
__global__ void k_collect(const u64* __restrict__ key, const uint32_t* __restrict__ prefix16,
                          uint32_t* __restrict__ cnt, uint32_t* __restrict__ ccnt,
                          u64* __restrict__ selk, u64* __restrict__ cand) {
    int gid = blockIdx.x * blockDim.x + threadIdx.x;
    int b = gid >> 15;
    u64 k = key[gid];
    uint32_t p16 = (uint32_t)(k >> 48);
    uint32_t pb = prefix16[b];
    bool def = p16 > pb;
    u64 mask = __ballot(def);
    int lane = threadIdx.x & 63;
    int wave = threadIdx.x >> 6;
    __shared__ uint32_t wtot[4], wbase[4], blockbase;
    uint32_t rank = lane ? (uint32_t)__popcll(mask & ((~0ull) >> (64 - lane))) : 0u;
    if (lane == 0) wtot[wave] = (uint32_t)__popcll(mask);
    __syncthreads();
    if (threadIdx.x == 0) {
        uint32_t t = 0;
        for (int w = 0; w < 4; ++w) { wbase[w] = t; t += wtot[w]; }
        blockbase = atomicAdd(&cnt[b], t);
    }
    __syncthreads();
    if (def) {
        selk[(size_t)b * PRE + blockbase + wbase[wave] + rank] = k;
    } else if (p16 == pb) {
        uint32_t pos = atomicAdd(&ccnt[b], 1u);
        if (pos < CANDCAP) cand[(size_t)b * CANDCAP + pos] = k;
    }
}

// 4) sort boundary candidates (bitonic, runtime pow2 <= CANDCAP), append top kneed to selk
__global__ void __launch_bounds__(256) k_final(const u64* __restrict__ cand,
                                               const uint32_t* __restrict__ ccnt,
                                               const uint32_t* __restrict__ kneed,
                                               const uint32_t* __restrict__ cnt,
                                               u64* __restrict__ selk) {
    int b = blockIdx.x;
    __shared__ u64 s[CANDCAP];
    uint32_t n = ccnt[b];
    if (n > CANDCAP) n = CANDCAP;
    uint32_t kn = kneed[b];
    uint32_t m = 64;
    while (m < n) m <<= 1;
    for (uint32_t i = threadIdx.x; i < m; i += blockDim.x)
        s[i] = (i < n) ? cand[(size_t)b * CANDCAP + i] : 0ull;
    __syncthreads();
    for (uint32_t k = 2; k <= m; k <<= 1) {
        for (uint32_t j = k >> 1; j > 0; j >>= 1) {
            for (uint32_t i = threadIdx.x; i < m; i += blockDim.x) {
                uint32_t ixj = i ^ j;
                if (ixj > i) {
                    u64 a = s[i], c2 = s[ixj];
                    bool desc = ((i & k) == 0);
                    if (desc ? (a < c2) : (a > c2)) { s[i] = c2; s[ixj] = a; }
                }
            }
            __syncthreads();
        }
    }
    uint32_t base = cnt[b];   // == PRE - kn
    for (uint32_t i = threadIdx.x; i < kn; i += blockDim.x)
        selk[(size_t)b * PRE + base + i] = s[i];
}

// 5) counting rank: keys distinct => rank(k) = #{k' > k}. Scatter at exact rank.
__global__ void __launch_bounds__(256) k_rank(const u64* __restrict__ selk,
                                              const float* __restrict__ box,
                                              int* __restrict__ sidx, float* __restrict__ ssc,
                                              float* __restrict__ bf) {
    int b = blockIdx.x / RANK_BPI;
    int c = blockIdx.x % RANK_BPI;
    const u64* sk = selk + (size_t)b * PRE;
    u64 myk = sk[c * 256 + threadIdx.x];
    __shared__ u64 tile[1024];
    int cnt = 0;
    for (int t0 = 0; t0 < PRE; t0 += 1024) {
        for (int i = threadIdx.x; i < 1024; i += 256) tile[i] = sk[t0 + i];
        __syncthreads();
#pragma unroll 16
        for (int j = 0; j < 1024; ++j) cnt += (tile[j] > myk) ? 1 : 0;
        __syncthreads();
    }
    int r = cnt;   // descending rank, exact (keys distinct)
    int n = (int)(~(uint32_t)(myk & 0xFFFFFFFFull));
    float sc = u2f((uint32_t)(myk >> 32));
    sidx[b * PRE + r] = n;
    ssc[b * PRE + r] = sc;
    const float* bp = box + ((size_t)b * NN + n) * 7;
    float x = bp[0], y = bp[1], dx = bp[3], dy = bp[4];
    float* bfb = bf + (size_t)b * 5 * PRE;
    bfb[0 * PRE + r] = x - dx * 0.5f;
    bfb[1 * PRE + r] = x + dx * 0.5f;
    bfb[2 * PRE + r] = y - dy * 0.5f;
    bfb[3 * PRE + r] = y + dy * 0.5f;
    bfb[4 * PRE + r] = dx * dy;
}

// 6) suppression rows [0,ROWS_END) x cols [0, WORDS*64): one wave per row,
//    word w = __ballot over lanes at j = w*64+lane (coalesced bf reads).
template<int ROWS_END, int WORDS, bool CHECK_FLAG>
__global__ void k_iou_t(const float* __restrict__ bf, u64* __restrict__ sup,
                        const uint32_t* __restrict__ flag) {
    const int bpi = ROWS_END / 4;            // blocks per item (4 waves/block)
    int b = blockIdx.x / bpi;
    if (CHECK_FLAG && flag[b]) return;
    int wave = threadIdx.x >> 6;
    int lane = threadIdx.x & 63;
    int i = (blockIdx.x % bpi) * 4 + wave;
    const float* bfb = bf + (size_t)b * 5 * PRE;
    float x1 = bfb[0 * PRE + i], x2 = bfb[1 * PRE + i];
    float y1 = bfb[2 * PRE + i], y2 = bfb[3 * PRE + i];
    float ar = bfb[4 * PRE + i];
    u64 myword = 0;
    for (int jw = 0; jw < WORDS; ++jw) {
        int j = jw * 64 + lane;
        float jx1 = bfb[0 * PRE + j], jx2 = bfb[1 * PRE + j];
        float jy1 = bfb[2 * PRE + j], jy2 = bfb[3 * PRE + j];
        float jar = bfb[4 * PRE + j];
        float ix = fminf(x2, jx2) - fmaxf(x1, jx1);
        ix = fmaxf(ix, 0.0f);
        float iy = fminf(y2, jy2) - fmaxf(y1, jy1);
        iy = fmaxf(iy, 0.0f);
        float inter = __fmul_rn(ix, iy);            // block FMA contraction (match np rounding)
        float uni = (ar + jar) - inter;
        float iou = inter / fmaxf(uni, 1e-6f);
        u64 bal = __ballot((iou > TH) && (j > i));
        if (jw == lane) myword = bal;
    }
    if (lane < WORDS) sup[((size_t)b * PRE + i) * 64 + lane] = myword;
}

__device__ __forceinline__ uint32_t kept_count(u64 removed, int words, int lane) {
    int v = (lane < words) ? __popcll(~removed) : 0;
#pragma unroll
    for (int off = 32; off > 0; off >>= 1) v += __shfl_xor(v, off, 64);
    return (uint32_t)v;
}

// 7) greedy scan rows [0,END), words < WORDS: 1 wave/item, lane w owns removed-word w.
//    __launch_bounds__(64,1): allow full VGPR budget so the 16+16 u64 double-buffer
//    stays in registers (default budget spilled it to scratch -> 54us; no-spill ~8us).
//    Early exit once POST kept rows finalized (checked every 64 rows).
template<int END, int WORDS, bool CHECK_FLAG>
__global__ void __launch_bounds__(64, 1) k_scan_t(const u64* __restrict__ sup,
                                                  u64* __restrict__ keepm,
                                                  uint32_t* __restrict__ flag) {
    const int CH = 16;
    int b = blockIdx.x;
    int lane = threadIdx.x;   // 64 threads = 1 wave
    if (CHECK_FLAG && flag[b]) return;
    bool act = lane < WORDS;
    u64 removed = 0;
    const u64* sb = sup + (size_t)b * PRE * 64;

    u64 bufA[CH], bufB[CH];
#pragma unroll
    for (int p = 0; p < CH; ++p) bufA[p] = act ? sb[(size_t)p * 64 + lane] : 0ull;

    bool fin = false;
    int S = END;
    for (int g = 0; g < END; g += 2 * CH) {
#pragma unroll
        for (int p = 0; p < CH; ++p) bufB[p] = act ? sb[(size_t)(g + CH + p) * 64 + lane] : 0ull;
#pragma unroll
        for (int p = 0; p < CH; ++p) {
            int i = g + p;
            u64 rw = __shfl(removed, i >> 6, 64);
            if (!((rw >> (i & 63)) & 1ull)) removed |= bufA[p];
        }
        if (g + 2 * CH < END) {
#pragma unroll
            for (int p = 0; p < CH; ++p) bufA[p] = act ? sb[(size_t)(g + 2 * CH + p) * 64 + lane] : 0ull;
        }
#pragma unroll
        for (int p = 0; p < CH; ++p) {
            int i = g + CH + p;
            u64 rw = __shfl(removed, i >> 6, 64);
            if (!((rw >> (i & 63)) & 1ull)) removed |= bufB[p];
        }
        if (((g + 2 * CH) & 63) == 0) {   // finalized-row multiple of 64
            uint32_t kept = kept_count(removed, (g + 2 * CH) >> 6, lane);
            if (kept >= POST) { S = g + 2 * CH; fin = true; break; }
        }
    }

    if (fin || END == PRE) {
        int words = S >> 6;
        keepm[b * 64 + lane] = (lane < words) ? ~removed : 0ull;
        if (lane == 0) flag[b] = 1;
    } else {
        if (lane == 0) flag[b] = 0;   // phase B does full recompute + rescan
    }
}

// 8) outputs: destination = position in argsort(where(keep, rank, PRE))
__global__ void __launch_bounds__(512) k_out(const u64* __restrict__ keepm,
                                             const int* __restrict__ sidx,
                                             const float* __restrict__ ssc,
                                             const float* __restrict__ box,
                                             const float* __restrict__ cls,
                                             float* __restrict__ out) {
    int b = blockIdx.x;
    __shared__ uint32_t wpre[65];
    const u64* km = keepm + b * 64;
    if (threadIdx.x == 0) {
        uint32_t c = 0;
        for (int w = 0; w < 64; ++w) { wpre[w] = c; c += (uint32_t)__popcll(km[w]); }
        wpre[64] = c;
    }
    __syncthreads();
    uint32_t nkeep = wpre[64];
    for (int r = threadIdx.x; r < PRE; r += blockDim.x) {
        int w = r >> 6, bit = r & 63;
        u64 word = km[w];
        bool kept = (word >> bit) & 1ull;
        u64 mask = bit ? ((1ull << bit) - 1ull) : 0ull;
        uint32_t before = wpre[w] + (uint32_t)__popcll(word & mask);
        uint32_t d = kept ? before : (nkeep + (uint32_t)r - before);
        if (d < POST) {
            float* ro = out + ((size_t)b * POST + d) * 7;
            float* so = out + (size_t)BB * POST * 7 + b * POST + d;
            float* lo = out + (size_t)BB * POST * 8 + b * POST + d;
            if (kept) {
                int n = sidx[b * PRE + r];
                const float* bp = box + ((size_t)b * NN + n) * 7;
#pragma unroll
                for (int t = 0; t < 7; ++t) ro[t] = bp[t];
                *so = ssc[b * PRE + r];
                const float* cp = cls + ((size_t)b * NN + n) * CC;
                float c0 = cp[0], c1 = cp[1], c2 = cp[2];
                int lbl = 0; float bst = c0;
                if (c1 > bst) { bst = c1; lbl = 1; }
                if (c2 > bst) { lbl = 2; }
                *lo = (float)(lbl + 1);
            } else {
#pragma unroll
                for (int t = 0; t < 7; ++t) ro[t] = 0.0f;
                *so = 0.0f;
                *lo = 1.0f;
            }
        }
    }
}

extern "C" void kernel_launch(void* const* d_in, const int* in_sizes, int n_in,
                              void* d_out, int out_size, void* d_ws, size_t ws_size,
                              hipStream_t stream) {
    const float* cls = (const float*)d_in[0];   // (4, 32768, 3)
    const float* box = (const float*)d_in[1];   // (4, 32768, 7)
    float* out = (float*)d_out;                 // 18432 floats

    char* ws = (char*)d_ws;
    const size_t MB = 1024 * 1024;
    // sup occupies [0, 8MB); key/hists/cand/selk alias inside it.
    // Phase-A iou writes only sup rows<768 (bytes [b*2MB, b*2MB+393KB)); by then
    // key/hist/cand/selk are all dead (k_rank ran). Phase-B (fallback) rewrites all it reads.
    size_t OFF_SUP   = 0;
    size_t OFF_KEY   = 0;                        // 1 MB
    size_t OFF_HISTF = 1 * MB;                   // 1 MB  (4 x 65536 x 4)
    size_t OFF_HISTC = 2 * MB;                   // 4 KB  (4 x 256 x 4)
    size_t OFF_CAND  = 2 * MB + 4096;            // 128 KB (4 x 4096 x 8)
    size_t OFF_SELK  = 3 * MB;                   // 128 KB
    size_t OFF_BF    = 8 * MB;                   // 320 KB
    size_t OFF_SIDX  = OFF_BF + (size_t)BB * 5 * PRE * 4;
    size_t OFF_SSC   = OFF_SIDX + (size_t)BB * PRE * 4;
    size_t OFF_KEEP  = OFF_SSC + (size_t)BB * PRE * 4;
    size_t OFF_SCAL  = OFF_KEEP + (size_t)BB * 64 * 8;   // cnt[4],ccnt[4],flag[4],pad
    size_t OFF_PFX   = OFF_SCAL + 64;                    // prefix16[4], kneed[4]

    u64*      sup    = (u64*)(ws + OFF_SUP);
    u64*      key    = (u64*)(ws + OFF_KEY);
    uint32_t* hist_f = (uint32_t*)(ws + OFF_HISTF);
    uint32_t* hist_c = (uint32_t*)(ws + OFF_HISTC);
    u64*      cand   = (u64*)(ws + OFF_CAND);
    u64*      selk   = (u64*)(ws + OFF_SELK);
    float*    bf     = (float*)(ws + OFF_BF);
    int*      sidx   = (int*)(ws + OFF_SIDX);
    float*    ssc    = (float*)(ws + OFF_SSC);
    u64*      keepm  = (u64*)(ws + OFF_KEEP);
    uint32_t* scal   = (uint32_t*)(ws + OFF_SCAL);
    uint32_t* cnt    = scal;
    uint32_t* ccnt   = scal + 4;
    uint32_t* flag   = scal + 8;
    uint32_t* prefix16 = (uint32_t*)(ws + OFF_PFX);
    uint32_t* kneed  = prefix16 + 4;

    // zero hist_f + hist_c (contiguous 1MB+4KB) and counters
    int n16 = (int)((MB + 4096) / 16);
    k_zero<<<(n16 + 255) / 256, 256, 0, stream>>>((uint4*)(ws + OFF_HISTF), scal, n16);
    k_keys_hist<<<(BB * NN) / 256, 256, 0, stream>>>(cls, key, hist_f, hist_c);
    k_choose<<<BB, 256, 0, stream>>>(hist_c, hist_f, prefix16, kneed);
    k_collect<<<(BB * NN) / 256, 256, 0, stream>>>(key, prefix16, cnt, ccnt, selk, cand);
    k_final<<<BB, 256, 0, stream>>>(cand, ccnt, kneed, cnt, selk);
    k_rank<<<BB * RANK_BPI, 256, 0, stream>>>(selk, box, sidx, ssc, bf);

    // Phase A: 768x768 sub-matrix (12 words/row) + early-exit scan
    k_iou_t<ROWS_A, ROWS_A / 64, false><<<(ROWS_A / 4) * BB, 256, 0, stream>>>(bf, sup, flag);
    k_scan_t<ROWS_A, ROWS_A / 64, false><<<BB, 64, 0, stream>>>(sup, keepm, flag);
    // Phase B (fallback, per-item no-op when flag==1): full 4096x4096 matrix + full rescan
    k_iou_t<PRE, 64, true><<<(PRE / 4) * BB, 256, 0, stream>>>(bf, sup, flag);
    k_scan_t<PRE, 64, true><<<BB, 64, 0, stream>>>(sup, keepm, flag);

    k_out<<<BB, 512, 0, stream>>>(keepm, sidx, ssc, box, cls, out);
}

// Round 6
// 146.045 us; speedup vs baseline: 14.1513x; 1.1743x over previous
//
#include <hip/hip_runtime.h>
#include <stdint.h>

typedef unsigned long long u64;

#define BB 4
#define NN 32768
#define CC 3
#define PRE 4096
#define POST 512
#define TH 0.7f
#define ROWS_A 768    // phase-A rows AND cols (12 words); early exit expected ~576-640
#define CANDCAP 4096
#define RANK_BPI 16   // rank blocks per item

__device__ __forceinline__ uint32_t f2u(float f) {
    uint32_t b = __float_as_uint(f);
    return (b & 0x80000000u) ? ~b : (b | 0x80000000u);
}
__device__ __forceinline__ float u2f(uint32_t u) {
    uint32_t b = (u & 0x80000000u) ? (u & 0x7FFFFFFFu) : ~u;
    return __uint_as_float(b);
}

// 0) zero hist region (uint4 stride) + scalar counters
__global__ void k_zero(uint4* __restrict__ histreg, uint32_t* __restrict__ scal, int n16) {
    int gid = blockIdx.x * blockDim.x + threadIdx.x;
    if (gid < n16) histreg[gid] = make_uint4(0, 0, 0, 0);
    if (gid < 16) scal[gid] = 0;
}

// 1) keys + 2-level histogram of top-16 key bits.
//    key = (orderable(score)<<32) | ~index  (distinct keys => exact top_k tie-break)
__global__ void k_keys_hist(const float* __restrict__ cls, u64* __restrict__ key,
                            uint32_t* __restrict__ hist_f, uint32_t* __restrict__ hist_c) {
    __shared__ uint32_t lc[256];
    lc[threadIdx.x] = 0;
    __syncthreads();
    int gid = blockIdx.x * blockDim.x + threadIdx.x;   // 512 blocks x 256
    int b = gid >> 15;
    const float* p = cls + (size_t)gid * CC;
    float s = fmaxf(fmaxf(p[0], p[1]), p[2]);
    int n = gid & (NN - 1);
    u64 kk = ((u64)f2u(s) << 32) | (uint32_t)(~(uint32_t)n);
    key[gid] = kk;
    uint32_t p16 = (uint32_t)(kk >> 48);
    atomicAdd(&hist_f[((uint32_t)b << 16) + p16], 1u);
    atomicAdd(&lc[p16 >> 8], 1u);
    __syncthreads();
    uint32_t v = lc[threadIdx.x];
    if (v) atomicAdd(&hist_c[((uint32_t)b << 8) + threadIdx.x], v);   // block spans one item
}

// 2) choose 16-bit threshold prefix: smallest p16 with (count of keys whose top16 > p16) < PRE
__global__ void k_choose(const uint32_t* __restrict__ hist_c, const uint32_t* __restrict__ hist_f,
                         uint32_t* __restrict__ prefix16, uint32_t* __restrict__ kneed) {
    int b = blockIdx.x;
    __shared__ uint32_t c[256];
    __shared__ uint32_t sel_c, rem_c;
    c[threadIdx.x] = hist_c[(b << 8) + threadIdx.x];
    __syncthreads();
    if (threadIdx.x == 0) {
        uint32_t need = PRE, cum = 0; int cc = 0;
        for (int d = 255; d >= 0; --d) {
            if (need <= cum + c[d]) { cc = d; break; }
            cum += c[d];
        }
        sel_c = (uint32_t)cc; rem_c = need - cum;
    }
    __syncthreads();
    c[threadIdx.x] = hist_f[((uint32_t)b << 16) + (sel_c << 8) + threadIdx.x];
    __syncthreads();
    if (threadIdx.x == 0) {
        uint32_t need = rem_c, cum = 0; int ff = 0;
        for (int d = 255; d >= 0; --d) {
            if (need <= cum + c[d]) { ff = d; break; }
            cum += c[d];
        }
        prefix16[b] = (sel_c << 8) | (uint32_t)ff;
        kneed[b] = need - cum;
    }
}

// 3) collect: definite winners (p16 > p*) via block-aggregated compaction (1 atomic/block),
//    boundary-bin candidates (p16 == p*) via per-thread atomic (tiny count)
__global__ void k_collect(const u64* __restrict__ key, const uint32_t* __restrict__ prefix16,
                          uint32_t* __restrict__ cnt, uint32_t* __restrict__ ccnt,
                          u64* __restrict__ selk, u64* __restrict__ cand) {
    int gid = blockIdx.x * blockDim.x + threadIdx.x;
    int b = gid >> 15;
    u64 k = key[gid];
    uint32_t p16 = (uint32_t)(k >> 48);
    uint32_t pb = prefix16[b];
    bool def = p16 > pb;
    u64 mask = __ballot(def);
    int lane = threadIdx.x & 63;
    int wave = threadIdx.x >> 6;
    __shared__ uint32_t wtot[4], wbase[4], blockbase;
    uint32_t rank = lane ? (uint32_t)__popcll(mask & ((~0ull) >> (64 - lane))) : 0u;
    if (lane == 0) wtot[wave] = (uint32_t)__popcll(mask);
    __syncthreads();
    if (threadIdx.x == 0) {
        uint32_t t = 0;
        for (int w = 0; w < 4; ++w) { wbase[w] = t; t += wtot[w]; }
        blockbase = atomicAdd(&cnt[b], t);
    }
    __syncthreads();
    if (def) {
        selk[(size_t)b * PRE + blockbase + wbase[wave] + rank] = k;
    } else if (p16 == pb) {
        uint32_t pos = atomicAdd(&ccnt[b], 1u);
        if (pos < CANDCAP) cand[(size_t)b * CANDCAP + pos] = k;
    }
}

// 4) sort boundary candidates (bitonic, runtime pow2 <= CANDCAP), append top kneed to selk
__global__ void __launch_bounds__(256) k_final(const u64* __restrict__ cand,
                                               const uint32_t* __restrict__ ccnt,
                                               const uint32_t* __restrict__ kneed,
                                               const uint32_t* __restrict__ cnt,
                                               u64* __restrict__ selk) {
    int b = blockIdx.x;
    __shared__ u64 s[CANDCAP];
    uint32_t n = ccnt[b];
    if (n > CANDCAP) n = CANDCAP;
    uint32_t kn = kneed[b];
    uint32_t m = 64;
    while (m < n) m <<= 1;
    for (uint32_t i = threadIdx.x; i < m; i += blockDim.x)
        s[i] = (i < n) ? cand[(size_t)b * CANDCAP + i] : 0ull;
    __syncthreads();
    for (uint32_t k = 2; k <= m; k <<= 1) {
        for (uint32_t j = k >> 1; j > 0; j >>= 1) {
            for (uint32_t i = threadIdx.x; i < m; i += blockDim.x) {
                uint32_t ixj = i ^ j;
                if (ixj > i) {
                    u64 a = s[i], c2 = s[ixj];
                    bool desc = ((i & k) == 0);
                    if (desc ? (a < c2) : (a > c2)) { s[i] = c2; s[ixj] = a; }
                }
            }
            __syncthreads();
        }
    }
    uint32_t base = cnt[b];   // == PRE - kn
    for (uint32_t i = threadIdx.x; i < kn; i += blockDim.x)
        selk[(size_t)b * PRE + base + i] = s[i];
}

// 5) counting rank: keys distinct => rank(k) = #{k' > k}. Scatter at exact rank.
__global__ void __launch_bounds__(256) k_rank(const u64* __restrict__ selk,
                                              const float* __restrict__ box,
                                              int* __restrict__ sidx, float* __restrict__ ssc,
                                              float* __restrict__ bf) {
    int b = blockIdx.x / RANK_BPI;
    int c = blockIdx.x % RANK_BPI;
    const u64* sk = selk + (size_t)b * PRE;
    u64 myk = sk[c * 256 + threadIdx.x];
    __shared__ u64 tile[1024];
    int cnt = 0;
    for (int t0 = 0; t0 < PRE; t0 += 1024) {
        for (int i = threadIdx.x; i < 1024; i += 256) tile[i] = sk[t0 + i];
        __syncthreads();
#pragma unroll 16
        for (int j = 0; j < 1024; ++j) cnt += (tile[j] > myk) ? 1 : 0;
        __syncthreads();
    }
    int r = cnt;   // descending rank, exact (keys distinct)
    int n = (int)(~(uint32_t)(myk & 0xFFFFFFFFull));
    float sc = u2f((uint32_t)(myk >> 32));
    sidx[b * PRE + r] = n;
    ssc[b * PRE + r] = sc;
    const float* bp = box + ((size_t)b * NN + n) * 7;
    float x = bp[0], y = bp[1], dx = bp[3], dy = bp[4];
    float* bfb = bf + (size_t)b * 5 * PRE;
    bfb[0 * PRE + r] = x - dx * 0.5f;
    bfb[1 * PRE + r] = x + dx * 0.5f;
    bfb[2 * PRE + r] = y - dy * 0.5f;
    bfb[3 * PRE + r] = y + dy * 0.5f;
    bfb[4 * PRE + r] = dx * dy;
}

// 6) suppression rows [0,ROWS_END) x cols [0, WORDS*64): one wave per row,
//    word w = __ballot over lanes at j = w*64+lane (coalesced bf reads).
template<int ROWS_END, int WORDS, bool CHECK_FLAG>
__global__ void k_iou_t(const float* __restrict__ bf, u64* __restrict__ sup,
                        const uint32_t* __restrict__ flag) {
    const int bpi = ROWS_END / 4;            // blocks per item (4 waves/block)
    int b = blockIdx.x / bpi;
    if (CHECK_FLAG && flag[b]) return;
    int wave = threadIdx.x >> 6;
    int lane = threadIdx.x & 63;
    int i = (blockIdx.x % bpi) * 4 + wave;
    const float* bfb = bf + (size_t)b * 5 * PRE;
    float x1 = bfb[0 * PRE + i], x2 = bfb[1 * PRE + i];
    float y1 = bfb[2 * PRE + i], y2 = bfb[3 * PRE + i];
    float ar = bfb[4 * PRE + i];
    u64 myword = 0;
    for (int jw = 0; jw < WORDS; ++jw) {
        int j = jw * 64 + lane;
        float jx1 = bfb[0 * PRE + j], jx2 = bfb[1 * PRE + j];
        float jy1 = bfb[2 * PRE + j], jy2 = bfb[3 * PRE + j];
        float jar = bfb[4 * PRE + j];
        float ix = fminf(x2, jx2) - fmaxf(x1, jx1);
        ix = fmaxf(ix, 0.0f);
        float iy = fminf(y2, jy2) - fmaxf(y1, jy1);
        iy = fmaxf(iy, 0.0f);
        float inter = __fmul_rn(ix, iy);            // block FMA contraction (match np rounding)
        float uni = (ar + jar) - inter;
        float iou = inter / fmaxf(uni, 1e-6f);
        u64 bal = __ballot((iou > TH) && (j > i));
        if (jw == lane) myword = bal;
    }
    if (lane < WORDS) sup[((size_t)b * PRE + i) * 64 + lane] = myword;
}

__device__ __forceinline__ uint32_t kept_count(u64 removed, int words, int lane) {
    int v = (lane < words) ? __popcll(~removed) : 0;
#pragma unroll
    for (int off = 32; off > 0; off >>= 1) v += __shfl_xor(v, off, 64);
    return (uint32_t)v;
}

// 7) greedy scan rows [0,END): 1 wave/item, lane w owns removed-word w.
//    Decision broadcast via __ballot (pure VALU/vcc, no ds_bpermute):
//      each lane tests bit (i&63) of ITS word; ballot packs predicates;
//      every lane reads uniform bit (i>>6). Lanes >= WORDS carry garbage
//      that is never consumed (ballot bit index < WORDS; keepm masked).
//    Loads are UNconditional (rows/words allocated for all 64 lanes) so the
//    compiler keeps the 16+16-row double-buffer in VGPRs (prev guarded
//    version sank loads -> ~4-deep prefetch -> 52us at ~900cy latency).
//    Early exit once POST kept rows finalized (checked per 64 rows).
template<int END, int WORDS, bool CHECK_FLAG>
__global__ void __launch_bounds__(64, 1) k_scan_t(const u64* __restrict__ sup,
                                                  u64* __restrict__ keepm,
                                                  uint32_t* __restrict__ flag) {
    const int CH = 16;
    int b = blockIdx.x;
    int lane = threadIdx.x;   // 64 threads = 1 wave
    if (CHECK_FLAG && flag[b]) return;
    u64 removed = 0;
    const u64* sb = sup + (size_t)b * PRE * 64;

    u64 bufA[CH], bufB[CH];
#pragma unroll
    for (int p = 0; p < CH; ++p) bufA[p] = sb[(size_t)p * 64 + lane];

    bool fin = false;
    int S = END;
    for (int g = 0; g < END; g += 2 * CH) {
#pragma unroll
        for (int p = 0; p < CH; ++p) bufB[p] = sb[(size_t)(g + CH + p) * 64 + lane];
#pragma unroll
        for (int p = 0; p < CH; ++p) {
            int i = g + p;
            u64 bal = __ballot(((removed >> (i & 63)) & 1ull) != 0ull);
            u64 rmmask = ((bal >> (i >> 6)) & 1ull) ? 0ull : ~0ull;
            removed |= bufA[p] & rmmask;
        }
        if (g + 2 * CH < END) {
#pragma unroll
            for (int p = 0; p < CH; ++p) bufA[p] = sb[(size_t)(g + 2 * CH + p) * 64 + lane];
        }
#pragma unroll
        for (int p = 0; p < CH; ++p) {
            int i = g + CH + p;
            u64 bal = __ballot(((removed >> (i & 63)) & 1ull) != 0ull);
            u64 rmmask = ((bal >> (i >> 6)) & 1ull) ? 0ull : ~0ull;
            removed |= bufB[p] & rmmask;
        }
        int done = g + 2 * CH;
        if ((done & 63) == 0 && done >= POST + 64) {   // first possible exit: 576 rows
            uint32_t kept = kept_count(removed, done >> 6, lane);
            if (kept >= POST) { S = done; fin = true; break; }
        }
    }

    if (fin || END == PRE) {
        int words = S >> 6;
        keepm[b * 64 + lane] = (lane < words) ? ~removed : 0ull;
        if (lane == 0) flag[b] = 1;
    } else {
        if (lane == 0) flag[b] = 0;   // phase B does full recompute + rescan
    }
}

// 8) outputs: destination = position in argsort(where(keep, rank, PRE))
__global__ void __launch_bounds__(512) k_out(const u64* __restrict__ keepm,
                                             const int* __restrict__ sidx,
                                             const float* __restrict__ ssc,
                                             const float* __restrict__ box,
                                             const float* __restrict__ cls,
                                             float* __restrict__ out) {
    int b = blockIdx.x;
    __shared__ uint32_t wpre[65];
    const u64* km = keepm + b * 64;
    if (threadIdx.x == 0) {
        uint32_t c = 0;
        for (int w = 0; w < 64; ++w) { wpre[w] = c; c += (uint32_t)__popcll(km[w]); }
        wpre[64] = c;
    }
    __syncthreads();
    uint32_t nkeep = wpre[64];
    for (int r = threadIdx.x; r < PRE; r += blockDim.x) {
        int w = r >> 6, bit = r & 63;
        u64 word = km[w];
        bool kept = (word >> bit) & 1ull;
        u64 mask = bit ? ((1ull << bit) - 1ull) : 0ull;
        uint32_t before = wpre[w] + (uint32_t)__popcll(word & mask);
        uint32_t d = kept ? before : (nkeep + (uint32_t)r - before);
        if (d < POST) {
            float* ro = out + ((size_t)b * POST + d) * 7;
            float* so = out + (size_t)BB * POST * 7 + b * POST + d;
            float* lo = out + (size_t)BB * POST * 8 + b * POST + d;
            if (kept) {
                int n = sidx[b * PRE + r];
                const float* bp = box + ((size_t)b * NN + n) * 7;
#pragma unroll
                for (int t = 0; t < 7; ++t) ro[t] = bp[t];
                *so = ssc[b * PRE + r];
                const float* cp = cls + ((size_t)b * NN + n) * CC;
                float c0 = cp[0], c1 = cp[1], c2 = cp[2];
                int lbl = 0; float bst = c0;
                if (c1 > bst) { bst = c1; lbl = 1; }
                if (c2 > bst) { lbl = 2; }
                *lo = (float)(lbl + 1);
            } else {
#pragma unroll
                for (int t = 0; t < 7; ++t) ro[t] = 0.0f;
                *so = 0.0f;
                *lo = 1.0f;
            }
        }
    }
}

extern "C" void kernel_launch(void* const* d_in, const int* in_sizes, int n_in,
                              void* d_out, int out_size, void* d_ws, size_t ws_size,
                              hipStream_t stream) {
    const float* cls = (const float*)d_in[0];   // (4, 32768, 3)
    const float* box = (const float*)d_in[1];   // (4, 32768, 7)
    float* out = (float*)d_out;                 // 18432 floats

    char* ws = (char*)d_ws;
    const size_t MB = 1024 * 1024;
    // sup occupies [0, 8MB); key/hists/cand/selk alias inside it.
    // Phase-A iou writes only sup rows<768 words<12; by then key/hist/cand/selk
    // are all dead (k_rank ran). Phase-B (fallback) rewrites everything it reads.
    size_t OFF_SUP   = 0;
    size_t OFF_KEY   = 0;                        // 1 MB
    size_t OFF_HISTF = 1 * MB;                   // 1 MB  (4 x 65536 x 4)
    size_t OFF_HISTC = 2 * MB;                   // 4 KB  (4 x 256 x 4)
    size_t OFF_CAND  = 2 * MB + 4096;            // 128 KB (4 x 4096 x 8)
    size_t OFF_SELK  = 3 * MB;                   // 128 KB
    size_t OFF_BF    = 8 * MB;                   // 320 KB
    size_t OFF_SIDX  = OFF_BF + (size_t)BB * 5 * PRE * 4;
    size_t OFF_SSC   = OFF_SIDX + (size_t)BB * PRE * 4;
    size_t OFF_KEEP  = OFF_SSC + (size_t)BB * PRE * 4;
    size_t OFF_SCAL  = OFF_KEEP + (size_t)BB * 64 * 8;   // cnt[4],ccnt[4],flag[4],pad
    size_t OFF_PFX   = OFF_SCAL + 64;                    // prefix16[4], kneed[4]

    u64*      sup    = (u64*)(ws + OFF_SUP);
    u64*      key    = (u64*)(ws + OFF_KEY);
    uint32_t* hist_f = (uint32_t*)(ws + OFF_HISTF);
    uint32_t* hist_c = (uint32_t*)(ws + OFF_HISTC);
    u64*      cand   = (u64*)(ws + OFF_CAND);
    u64*      selk   = (u64*)(ws + OFF_SELK);
    float*    bf     = (float*)(ws + OFF_BF);
    int*      sidx   = (int*)(ws + OFF_SIDX);
    float*    ssc    = (float*)(ws + OFF_SSC);
    u64*      keepm  = (u64*)(ws + OFF_KEEP);
    uint32_t* scal   = (uint32_t*)(ws + OFF_SCAL);
    uint32_t* cnt    = scal;
    uint32_t* ccnt   = scal + 4;
    uint32_t* flag   = scal + 8;
    uint32_t* prefix16 = (uint32_t*)(ws + OFF_PFX);
    uint32_t* kneed  = prefix16 + 4;

    // zero hist_f + hist_c (contiguous 1MB+4KB) and counters
    int n16 = (int)((MB + 4096) / 16);
    k_zero<<<(n16 + 255) / 256, 256, 0, stream>>>((uint4*)(ws + OFF_HISTF), scal, n16);
    k_keys_hist<<<(BB * NN) / 256, 256, 0, stream>>>(cls, key, hist_f, hist_c);
    k_choose<<<BB, 256, 0, stream>>>(hist_c, hist_f, prefix16, kneed);
    k_collect<<<(BB * NN) / 256, 256, 0, stream>>>(key, prefix16, cnt, ccnt, selk, cand);
    k_final<<<BB, 256, 0, stream>>>(cand, ccnt, kneed, cnt, selk);
    k_rank<<<BB * RANK_BPI, 256, 0, stream>>>(selk, box, sidx, ssc, bf);

    // Phase A: 768x768 sub-matrix (12 words/row) + early-exit scan
    k_iou_t<ROWS_A, ROWS_A / 64, false><<<(ROWS_A / 4) * BB, 256, 0, stream>>>(bf, sup, flag);
    k_scan_t<ROWS_A, ROWS_A / 64, false><<<BB, 64, 0, stream>>>(sup, keepm, flag);
    // Phase B (fallback, per-item no-op when flag==1): full 4096x4096 matrix + full rescan
    k_iou_t<PRE, 64, true><<<(PRE / 4) * BB, 256, 0, stream>>>(bf, sup, flag);
    k_scan_t<PRE, 64, true><<<BB, 64, 0, stream>>>(sup, keepm, flag);

    k_out<<<BB, 512, 0, stream>>>(keepm, sidx, ssc, box, cls, out);
}

// Round 7
// 113.134 us; speedup vs baseline: 18.2679x; 1.2909x over previous
//
#include <hip/hip_runtime.h>
#include <stdint.h>

typedef unsigned long long u64;

#define BB 4
#define NN 32768
#define CC 3
#define PRE 4096
#define POST 512
#define TH 0.7f
#define ROWS_A 768    // phase-A rows AND cols (12 words); early exit expected ~576-640
#define CANDCAP 4096
#define RANK_BPI 16   // rank key-chunks per item
#define COLSPLIT 4    // rank column-split (256 blocks total)

__device__ __forceinline__ uint32_t f2u(float f) {
    uint32_t b = __float_as_uint(f);
    return (b & 0x80000000u) ? ~b : (b | 0x80000000u);
}
__device__ __forceinline__ float u2f(uint32_t u) {
    uint32_t b = (u & 0x80000000u) ? (u & 0x7FFFFFFFu) : ~u;
    return __uint_as_float(b);
}

// 0) zero hist region + rank accumulators (uint4 stride) + scalar counters
__global__ void k_zero(uint4* __restrict__ histreg, uint4* __restrict__ rnk16,
                       uint32_t* __restrict__ scal, int n16, int nr16) {
    int gid = blockIdx.x * blockDim.x + threadIdx.x;
    if (gid < n16) histreg[gid] = make_uint4(0, 0, 0, 0);
    if (gid < nr16) rnk16[gid] = make_uint4(0, 0, 0, 0);
    if (gid < 16) scal[gid] = 0;
}

// 1) keys + 2-level histogram of top-16 key bits.
//    key = (orderable(score)<<32) | ~index  (distinct keys => exact top_k tie-break)
__global__ void k_keys_hist(const float* __restrict__ cls, u64* __restrict__ key,
                            uint32_t* __restrict__ hist_f, uint32_t* __restrict__ hist_c) {
    __shared__ uint32_t lc[256];
    lc[threadIdx.x] = 0;
    __syncthreads();
    int gid = blockIdx.x * blockDim.x + threadIdx.x;   // 512 blocks x 256
    int b = gid >> 15;
    const float* p = cls + (size_t)gid * CC;
    float s = fmaxf(fmaxf(p[0], p[1]), p[2]);
    int n = gid & (NN - 1);
    u64 kk = ((u64)f2u(s) << 32) | (uint32_t)(~(uint32_t)n);
    key[gid] = kk;
    uint32_t p16 = (uint32_t)(kk >> 48);
    atomicAdd(&hist_f[((uint32_t)b << 16) + p16], 1u);
    atomicAdd(&lc[p16 >> 8], 1u);
    __syncthreads();
    uint32_t v = lc[threadIdx.x];
    if (v) atomicAdd(&hist_c[((uint32_t)b << 8) + threadIdx.x], v);   // block spans one item
}

// 2) choose 16-bit threshold prefix: smallest p16 with (count of keys whose top16 > p16) < PRE
__global__ void k_choose(const uint32_t* __restrict__ hist_c, const uint32_t* __restrict__ hist_f,
                         uint32_t* __restrict__ prefix16, uint32_t* __restrict__ kneed) {
    int b = blockIdx.x;
    __shared__ uint32_t c[256];
    __shared__ uint32_t sel_c, rem_c;
    c[threadIdx.x] = hist_c[(b << 8) + threadIdx.x];
    __syncthreads();
    if (threadIdx.x == 0) {
        uint32_t need = PRE, cum = 0; int cc = 0;
        for (int d = 255; d >= 0; --d) {
            if (need <= cum + c[d]) { cc = d; break; }
            cum += c[d];
        }
        sel_c = (uint32_t)cc; rem_c = need - cum;
    }
    __syncthreads();
    c[threadIdx.x] = hist_f[((uint32_t)b << 16) + (sel_c << 8) + threadIdx.x];
    __syncthreads();
    if (threadIdx.x == 0) {
        uint32_t need = rem_c, cum = 0; int ff = 0;
        for (int d = 255; d >= 0; --d) {
            if (need <= cum + c[d]) { ff = d; break; }
            cum += c[d];
        }
        prefix16[b] = (sel_c << 8) | (uint32_t)ff;
        kneed[b] = need - cum;
    }
}

// 3) collect: definite winners (p16 > p*) via block-aggregated compaction (1 atomic/block),
//    boundary-bin candidates (p16 == p*) via per-thread atomic (tiny count)
__global__ void k_collect(const u64* __restrict__ key, const uint32_t* __restrict__ prefix16,
                          uint32_t* __restrict__ cnt, uint32_t* __restrict__ ccnt,
                          u64* __restrict__ selk, u64* __restrict__ cand) {
    int gid = blockIdx.x * blockDim.x + threadIdx.x;
    int b = gid >> 15;
    u64 k = key[gid];
    uint32_t p16 = (uint32_t)(k >> 48);
    uint32_t pb = prefix16[b];
    bool def = p16 > pb;
    u64 mask = __ballot(def);
    int lane = threadIdx.x & 63;
    int wave = threadIdx.x >> 6;
    __shared__ uint32_t wtot[4], wbase[4], blockbase;
    uint32_t rank = lane ? (uint32_t)__popcll(mask & ((~0ull) >> (64 - lane))) : 0u;
    if (lane == 0) wtot[wave] = (uint32_t)__popcll(mask);
    __syncthreads();
    if (threadIdx.x == 0) {
        uint32_t t = 0;
        for (int w = 0; w < 4; ++w) { wbase[w] = t; t += wtot[w]; }
        blockbase = atomicAdd(&cnt[b], t);
    }
    __syncthreads();
    if (def) {
        selk[(size_t)b * PRE + blockbase + wbase[wave] + rank] = k;
    } else if (p16 == pb) {
        uint32_t pos = atomicAdd(&ccnt[b], 1u);
        if (pos < CANDCAP) cand[(size_t)b * CANDCAP + pos] = k;
    }
}

// 4) sort boundary candidates (bitonic, runtime pow2 <= CANDCAP), append top kneed to selk
__global__ void __launch_bounds__(256) k_final(const u64* __restrict__ cand,
                                               const uint32_t* __restrict__ ccnt,
                                               const uint32_t* __restrict__ kneed,
                                               const uint32_t* __restrict__ cnt,
                                               u64* __restrict__ selk) {
    int b = blockIdx.x;
    __shared__ u64 s[CANDCAP];
    uint32_t n = ccnt[b];
    if (n > CANDCAP) n = CANDCAP;
    uint32_t kn = kneed[b];
    uint32_t m = 64;
    while (m < n) m <<= 1;
    for (uint32_t i = threadIdx.x; i < m; i += blockDim.x)
        s[i] = (i < n) ? cand[(size_t)b * CANDCAP + i] : 0ull;
    __syncthreads();
    for (uint32_t k = 2; k <= m; k <<= 1) {
        for (uint32_t j = k >> 1; j > 0; j >>= 1) {
            for (uint32_t i = threadIdx.x; i < m; i += blockDim.x) {
                uint32_t ixj = i ^ j;
                if (ixj > i) {
                    u64 a = s[i], c2 = s[ixj];
                    bool desc = ((i & k) == 0);
                    if (desc ? (a < c2) : (a > c2)) { s[i] = c2; s[ixj] = a; }
                }
            }
            __syncthreads();
        }
    }
    uint32_t base = cnt[b];   // == PRE - kn
    for (uint32_t i = threadIdx.x; i < kn; i += blockDim.x)
        selk[(size_t)b * PRE + base + i] = s[i];
}

// 5a) partial counting rank: keys distinct => rank(k) = #{k' > k} = sum of col-chunk counts.
//     grid = BB * RANK_BPI * COLSPLIT blocks (256 = all CUs), 256 threads.
//     Block (b, c, q): keys [c*256, c*256+256) vs cols [q*1024, q*1024+1024) via 8KB LDS tile.
__global__ void __launch_bounds__(256) k_rank_cnt(const u64* __restrict__ selk,
                                                  uint32_t* __restrict__ rnk) {
    int blk = blockIdx.x;
    int b = blk / (RANK_BPI * COLSPLIT);
    int r = blk % (RANK_BPI * COLSPLIT);
    int c = r / COLSPLIT;
    int q = r % COLSPLIT;
    const u64* sk = selk + (size_t)b * PRE;
    u64 myk = sk[c * 256 + threadIdx.x];
    __shared__ u64 tile[PRE / COLSPLIT];
    const int TS = PRE / COLSPLIT;   // 1024
    for (int i = threadIdx.x; i < TS; i += 256) tile[i] = sk[q * TS + i];
    __syncthreads();
    int cnt = 0;
#pragma unroll 16
    for (int j = 0; j < TS; ++j) cnt += (tile[j] > myk) ? 1 : 0;
    if (cnt) atomicAdd(&rnk[b * PRE + c * 256 + threadIdx.x], (uint32_t)cnt);
}

// 5b) scatter at final rank: gather box row, write sidx/ssc/bf
__global__ void __launch_bounds__(256) k_scatter(const u64* __restrict__ selk,
                                                 const uint32_t* __restrict__ rnk,
                                                 const float* __restrict__ box,
                                                 int* __restrict__ sidx, float* __restrict__ ssc,
                                                 float* __restrict__ bf) {
    int gid = blockIdx.x * blockDim.x + threadIdx.x;   // BB*PRE threads
    int b = gid >> 12;
    int i = gid & (PRE - 1);
    u64 myk = selk[(size_t)b * PRE + i];
    int r = (int)rnk[b * PRE + i];
    int n = (int)(~(uint32_t)(myk & 0xFFFFFFFFull));
    float sc = u2f((uint32_t)(myk >> 32));
    sidx[b * PRE + r] = n;
    ssc[b * PRE + r] = sc;
    const float* bp = box + ((size_t)b * NN + n) * 7;
    float x = bp[0], y = bp[1], dx = bp[3], dy = bp[4];
    float* bfb = bf + (size_t)b * 5 * PRE;
    bfb[0 * PRE + r] = x - dx * 0.5f;
    bfb[1 * PRE + r] = x + dx * 0.5f;
    bfb[2 * PRE + r] = y - dy * 0.5f;
    bfb[3 * PRE + r] = y + dy * 0.5f;
    bfb[4 * PRE + r] = dx * dy;
}

// 6) suppression rows [0,ROWS_END) x cols [0, WORDS*64): one wave per row,
//    word w = __ballot over lanes at j = w*64+lane (coalesced bf reads).
template<int ROWS_END, int WORDS, bool CHECK_FLAG>
__global__ void k_iou_t(const float* __restrict__ bf, u64* __restrict__ sup,
                        const uint32_t* __restrict__ flag) {
    const int bpi = ROWS_END / 4;            // blocks per item (4 waves/block)
    int b = blockIdx.x / bpi;
    if (CHECK_FLAG && flag[b]) return;
    int wave = threadIdx.x >> 6;
    int lane = threadIdx.x & 63;
    int i = (blockIdx.x % bpi) * 4 + wave;
    const float* bfb = bf + (size_t)b * 5 * PRE;
    float x1 = bfb[0 * PRE + i], x2 = bfb[1 * PRE + i];
    float y1 = bfb[2 * PRE + i], y2 = bfb[3 * PRE + i];
    float ar = bfb[4 * PRE + i];
    u64 myword = 0;
    for (int jw = 0; jw < WORDS; ++jw) {
        int j = jw * 64 + lane;
        float jx1 = bfb[0 * PRE + j], jx2 = bfb[1 * PRE + j];
        float jy1 = bfb[2 * PRE + j], jy2 = bfb[3 * PRE + j];
        float jar = bfb[4 * PRE + j];
        float ix = fminf(x2, jx2) - fmaxf(x1, jx1);
        ix = fmaxf(ix, 0.0f);
        float iy = fminf(y2, jy2) - fmaxf(y1, jy1);
        iy = fmaxf(iy, 0.0f);
        float inter = __fmul_rn(ix, iy);            // block FMA contraction (match np rounding)
        float uni = (ar + jar) - inter;
        float iou = inter / fmaxf(uni, 1e-6f);
        u64 bal = __ballot((iou > TH) && (j > i));
        if (jw == lane) myword = bal;
    }
    if (lane < WORDS) sup[((size_t)b * PRE + i) * 64 + lane] = myword;
}

__device__ __forceinline__ uint32_t kept_count(u64 removed, int words, int lane) {
    int v = (lane < words) ? __popcll(~removed) : 0;
#pragma unroll
    for (int off = 32; off > 0; off >>= 1) v += __shfl_xor(v, off, 64);
    return (uint32_t)v;
}

// 7) greedy scan rows [0,END): 1 wave/item, lane w owns removed-word w.
//    Decision broadcast via __ballot (pure VALU/vcc). Unconditional loads keep the
//    16+16-row double-buffer in VGPRs. Early exit once POST kept rows finalized.
template<int END, int WORDS, bool CHECK_FLAG>
__global__ void __launch_bounds__(64, 1) k_scan_t(const u64* __restrict__ sup,
                                                  u64* __restrict__ keepm,
                                                  uint32_t* __restrict__ flag) {
    const int CH = 16;
    int b = blockIdx.x;
    int lane = threadIdx.x;   // 64 threads = 1 wave
    if (CHECK_FLAG && flag[b]) return;
    u64 removed = 0;
    const u64* sb = sup + (size_t)b * PRE * 64;

    u64 bufA[CH], bufB[CH];
#pragma unroll
    for (int p = 0; p < CH; ++p) bufA[p] = sb[(size_t)p * 64 + lane];

    bool fin = false;
    int S = END;
    for (int g = 0; g < END; g += 2 * CH) {
#pragma unroll
        for (int p = 0; p < CH; ++p) bufB[p] = sb[(size_t)(g + CH + p) * 64 + lane];
#pragma unroll
        for (int p = 0; p < CH; ++p) {
            int i = g + p;
            u64 bal = __ballot(((removed >> (i & 63)) & 1ull) != 0ull);
            u64 rmmask = ((bal >> (i >> 6)) & 1ull) ? 0ull : ~0ull;
            removed |= bufA[p] & rmmask;
        }
        if (g + 2 * CH < END) {
#pragma unroll
            for (int p = 0; p < CH; ++p) bufA[p] = sb[(size_t)(g + 2 * CH + p) * 64 + lane];
        }
#pragma unroll
        for (int p = 0; p < CH; ++p) {
            int i = g + CH + p;
            u64 bal = __ballot(((removed >> (i & 63)) & 1ull) != 0ull);
            u64 rmmask = ((bal >> (i >> 6)) & 1ull) ? 0ull : ~0ull;
            removed |= bufB[p] & rmmask;
        }
        int done = g + 2 * CH;
        if ((done & 63) == 0 && done >= POST + 64) {   // first possible exit: 576 rows
            uint32_t kept = kept_count(removed, done >> 6, lane);
            if (kept >= POST) { S = done; fin = true; break; }
        }
    }

    if (fin || END == PRE) {
        int words = S >> 6;
        keepm[b * 64 + lane] = (lane < words) ? ~removed : 0ull;
        if (lane == 0) flag[b] = 1;
    } else {
        if (lane == 0) flag[b] = 0;   // phase B does full recompute + rescan
    }
}

// 8) outputs: destination = position in argsort(where(keep, rank, PRE))
__global__ void __launch_bounds__(512) k_out(const u64* __restrict__ keepm,
                                             const int* __restrict__ sidx,
                                             const float* __restrict__ ssc,
                                             const float* __restrict__ box,
                                             const float* __restrict__ cls,
                                             float* __restrict__ out) {
    int b = blockIdx.x;
    __shared__ uint32_t wpre[65];
    const u64* km = keepm + b * 64;
    if (threadIdx.x == 0) {
        uint32_t c = 0;
        for (int w = 0; w < 64; ++w) { wpre[w] = c; c += (uint32_t)__popcll(km[w]); }
        wpre[64] = c;
    }
    __syncthreads();
    uint32_t nkeep = wpre[64];
    for (int r = threadIdx.x; r < PRE; r += blockDim.x) {
        int w = r >> 6, bit = r & 63;
        u64 word = km[w];
        bool kept = (word >> bit) & 1ull;
        u64 mask = bit ? ((1ull << bit) - 1ull) : 0ull;
        uint32_t before = wpre[w] + (uint32_t)__popcll(word & mask);
        uint32_t d = kept ? before : (nkeep + (uint32_t)r - before);
        if (d < POST) {
            float* ro = out + ((size_t)b * POST + d) * 7;
            float* so = out + (size_t)BB * POST * 7 + b * POST + d;
            float* lo = out + (size_t)BB * POST * 8 + b * POST + d;
            if (kept) {
                int n = sidx[b * PRE + r];
                const float* bp = box + ((size_t)b * NN + n) * 7;
#pragma unroll
                for (int t = 0; t < 7; ++t) ro[t] = bp[t];
                *so = ssc[b * PRE + r];
                const float* cp = cls + ((size_t)b * NN + n) * CC;
                float c0 = cp[0], c1 = cp[1], c2 = cp[2];
                int lbl = 0; float bst = c0;
                if (c1 > bst) { bst = c1; lbl = 1; }
                if (c2 > bst) { lbl = 2; }
                *lo = (float)(lbl + 1);
            } else {
#pragma unroll
                for (int t = 0; t < 7; ++t) ro[t] = 0.0f;
                *so = 0.0f;
                *lo = 1.0f;
            }
        }
    }
}

extern "C" void kernel_launch(void* const* d_in, const int* in_sizes, int n_in,
                              void* d_out, int out_size, void* d_ws, size_t ws_size,
                              hipStream_t stream) {
    const float* cls = (const float*)d_in[0];   // (4, 32768, 3)
    const float* box = (const float*)d_in[1];   // (4, 32768, 7)
    float* out = (float*)d_out;                 // 18432 floats

    char* ws = (char*)d_ws;
    const size_t MB = 1024 * 1024;
    // sup occupies [0, 8MB); key/hists/cand/selk alias inside it.
    // Phase-A iou writes only sup rows<768 words<12; by then key/hist/cand are dead
    // (selk/rnk consumed by k_scatter which runs before iou). Phase-B rewrites all it reads.
    size_t OFF_SUP   = 0;
    size_t OFF_KEY   = 0;                        // 1 MB
    size_t OFF_HISTF = 1 * MB;                   // 1 MB  (4 x 65536 x 4)
    size_t OFF_HISTC = 2 * MB;                   // 4 KB  (4 x 256 x 4)
    size_t OFF_CAND  = 2 * MB + 4096;            // 128 KB (4 x 4096 x 8)
    size_t OFF_SELK  = 3 * MB;                   // 128 KB
    size_t OFF_RNK   = 4 * MB;                   // 64 KB (4 x 4096 x 4)
    size_t OFF_BF    = 8 * MB;                   // 320 KB
    size_t OFF_SIDX  = OFF_BF + (size_t)BB * 5 * PRE * 4;
    size_t OFF_SSC   = OFF_SIDX + (size_t)BB * PRE * 4;
    size_t OFF_KEEP  = OFF_SSC + (size_t)BB * PRE * 4;
    size_t OFF_SCAL  = OFF_KEEP + (size_t)BB * 64 * 8;   // cnt[4],ccnt[4],flag[4],pad
    size_t OFF_PFX   = OFF_SCAL + 64;                    // prefix16[4], kneed[4]

    u64*      sup    = (u64*)(ws + OFF_SUP);
    u64*      key    = (u64*)(ws + OFF_KEY);
    uint32_t* hist_f = (uint32_t*)(ws + OFF_HISTF);
    uint32_t* hist_c = (uint32_t*)(ws + OFF_HISTC);
    u64*      cand   = (u64*)(ws + OFF_CAND);
    u64*      selk   = (u64*)(ws + OFF_SELK);
    uint32_t* rnk    = (uint32_t*)(ws + OFF_RNK);
    float*    bf     = (float*)(ws + OFF_BF);
    int*      sidx   = (int*)(ws + OFF_SIDX);
    float*    ssc    = (float*)(ws + OFF_SSC);
    u64*      keepm  = (u64*)(ws + OFF_KEEP);
    uint32_t* scal   = (uint32_t*)(ws + OFF_SCAL);
    uint32_t* cnt    = scal;
    uint32_t* ccnt   = scal + 4;
    uint32_t* flag   = scal + 8;
    uint32_t* prefix16 = (uint32_t*)(ws + OFF_PFX);
    uint32_t* kneed  = prefix16 + 4;

    // zero hist_f + hist_c (contiguous 1MB+4KB), rnk (64KB), counters
    int n16 = (int)((MB + 4096) / 16);
    int nr16 = (int)((BB * PRE * 4) / 16);
    k_zero<<<(n16 + 255) / 256, 256, 0, stream>>>((uint4*)(ws + OFF_HISTF),
                                                  (uint4*)(ws + OFF_RNK), scal, n16, nr16);
    k_keys_hist<<<(BB * NN) / 256, 256, 0, stream>>>(cls, key, hist_f, hist_c);
    k_choose<<<BB, 256, 0, stream>>>(hist_c, hist_f, prefix16, kneed);
    k_collect<<<(BB * NN) / 256, 256, 0, stream>>>(key, prefix16, cnt, ccnt, selk, cand);
    k_final<<<BB, 256, 0, stream>>>(cand, ccnt, kneed, cnt, selk);
    k_rank_cnt<<<BB * RANK_BPI * COLSPLIT, 256, 0, stream>>>(selk, rnk);
    k_scatter<<<(BB * PRE) / 256, 256, 0, stream>>>(selk, rnk, box, sidx, ssc, bf);

    // Phase A: 768x768 sub-matrix (12 words/row) + early-exit scan
    k_iou_t<ROWS_A, ROWS_A / 64, false><<<(ROWS_A / 4) * BB, 256, 0, stream>>>(bf, sup, flag);
    k_scan_t<ROWS_A, ROWS_A / 64, false><<<BB, 64, 0, stream>>>(sup, keepm, flag);
    // Phase B (fallback, per-item no-op when flag==1): full 4096x4096 matrix + full rescan
    k_iou_t<PRE, 64, true><<<(PRE / 4) * BB, 256, 0, stream>>>(bf, sup, flag);
    k_scan_t<PRE, 64, true><<<BB, 64, 0, stream>>>(sup, keepm, flag);

    k_out<<<BB, 512, 0, stream>>>(keepm, sidx, ssc, box, cls, out);
}

// Round 8
// 103.786 us; speedup vs baseline: 19.9133x; 1.0901x over previous
//
#include <hip/hip_runtime.h>
#include <stdint.h>

typedef unsigned long long u64;

#define BB 4
#define NN 32768
#define CC 3
#define PRE 4096
#define POST 512
#define TH 0.7f
#define ROWS_A 768    // phase-A rows AND cols (12 words); early exit expected ~576-640
#define CANDCAP 4096
#define RS_KPB 64     // rankscatter keys per block

__device__ __forceinline__ uint32_t f2u(float f) {
    uint32_t b = __float_as_uint(f);
    return (b & 0x80000000u) ? ~b : (b | 0x80000000u);
}
__device__ __forceinline__ float u2f(uint32_t u) {
    uint32_t b = (u & 0x80000000u) ? (u & 0x7FFFFFFFu) : ~u;
    return __uint_as_float(b);
}
__device__ __forceinline__ float score3(const float* p) {
    return fmaxf(fmaxf(p[0], p[1]), p[2]);
}

// 0) zero hist region (uint4 stride) + scalar counters
__global__ void k_zero(uint4* __restrict__ histreg, uint32_t* __restrict__ scal, int n16) {
    int gid = blockIdx.x * blockDim.x + threadIdx.x;
    if (gid < n16) histreg[gid] = make_uint4(0, 0, 0, 0);
    if (gid < 16) scal[gid] = 0;
}

// 1) 2-level histogram of top-16 key bits (keys NOT materialized; recomputed later).
//    key = (orderable(score)<<32) | ~index  (distinct keys => exact top_k tie-break)
__global__ void k_hist(const float* __restrict__ cls,
                       uint32_t* __restrict__ hist_f, uint32_t* __restrict__ hist_c) {
    __shared__ uint32_t lc[256];
    lc[threadIdx.x] = 0;
    __syncthreads();
    int gid = blockIdx.x * blockDim.x + threadIdx.x;   // 512 blocks x 256; block spans one item
    int b = gid >> 15;
    uint32_t p16 = f2u(score3(cls + (size_t)gid * CC)) >> 16;
    atomicAdd(&hist_f[((uint32_t)b << 16) + p16], 1u);
    atomicAdd(&lc[p16 >> 8], 1u);
    __syncthreads();
    uint32_t v = lc[threadIdx.x];
    if (v) atomicAdd(&hist_c[((uint32_t)b << 8) + threadIdx.x], v);
}

// 2) collect (with fused threshold-choose): every block re-derives the 16-bit threshold
//    prefix via two parallel suffix-scans (coarse 256, then fine 256), then:
//    definite winners (p16 > pb) -> block-aggregated compaction (1 atomic/block);
//    boundary-bin candidates (p16 == pb) -> per-thread atomic (tiny count).
__global__ void __launch_bounds__(256) k_collect(const float* __restrict__ cls,
                                                 const uint32_t* __restrict__ hist_c,
                                                 const uint32_t* __restrict__ hist_f,
                                                 uint32_t* __restrict__ cnt,
                                                 uint32_t* __restrict__ ccnt,
                                                 u64* __restrict__ selk, u64* __restrict__ cand) {
    int tid = threadIdx.x;
    int gid = blockIdx.x * 256 + tid;
    int b = gid >> 15;
    __shared__ uint32_t pref[256];
    __shared__ uint32_t s_selc, s_remc, s_pb;

    // coarse suffix-scan: thread t owns coarse bin (255 - t), pref = inclusive sum from top
    uint32_t v = hist_c[((uint32_t)b << 8) + 255 - tid];
    pref[tid] = v;
    __syncthreads();
    for (int off = 1; off < 256; off <<= 1) {
        uint32_t x = (tid >= off) ? pref[tid - off] : 0;
        __syncthreads();
        pref[tid] += x;
        __syncthreads();
    }
    {
        uint32_t after = pref[tid], before = after - v;
        if (before < PRE && PRE <= after) { s_selc = 255 - tid; s_remc = PRE - before; }
    }
    __syncthreads();
    uint32_t selc = s_selc, remc = s_remc;
    // fine suffix-scan within chosen coarse bin
    uint32_t v2 = hist_f[((uint32_t)b << 16) + (selc << 8) + 255 - tid];
    __syncthreads();           // all reads of pref from coarse pass are done
    pref[tid] = v2;
    __syncthreads();
    for (int off = 1; off < 256; off <<= 1) {
        uint32_t x = (tid >= off) ? pref[tid - off] : 0;
        __syncthreads();
        pref[tid] += x;
        __syncthreads();
    }
    {
        uint32_t after = pref[tid], before = after - v2;
        if (before < remc && remc <= after) s_pb = (selc << 8) | (uint32_t)(255 - tid);
    }
    __syncthreads();
    uint32_t pb = s_pb;

    // recompute key for my element
    u64 k = ((u64)f2u(score3(cls + (size_t)gid * CC)) << 32)
          | (uint32_t)(~(uint32_t)(gid & (NN - 1)));
    uint32_t p16 = (uint32_t)(k >> 48);
    bool def = p16 > pb;
    u64 mask = __ballot(def);
    int lane = tid & 63;
    int wave = tid >> 6;
    __shared__ uint32_t wtot[4], wbase[4], blockbase;
    uint32_t rank = lane ? (uint32_t)__popcll(mask & ((~0ull) >> (64 - lane))) : 0u;
    if (lane == 0) wtot[wave] = (uint32_t)__popcll(mask);
    __syncthreads();
    if (tid == 0) {
        uint32_t t = 0;
        for (int w = 0; w < 4; ++w) { wbase[w] = t; t += wtot[w]; }
        blockbase = atomicAdd(&cnt[b], t);
    }
    __syncthreads();
    if (def) {
        selk[(size_t)b * PRE + blockbase + wbase[wave] + rank] = k;
    } else if (p16 == pb) {
        uint32_t pos = atomicAdd(&ccnt[b], 1u);
        if (pos < CANDCAP) cand[(size_t)b * CANDCAP + pos] = k;
    }
}

// 3) boundary bin: rank-placement (keys distinct, order-independent): candidate with
//    rank r (desc) lands at selk[base + r] iff r < kneed = PRE - base. O(c^2), c ~ 60.
__global__ void __launch_bounds__(256) k_final(const u64* __restrict__ cand,
                                               const uint32_t* __restrict__ ccnt,
                                               const uint32_t* __restrict__ cnt,
                                               u64* __restrict__ selk) {
    int b = blockIdx.x;
    __shared__ u64 s[CANDCAP];
    uint32_t n = ccnt[b];
    if (n > CANDCAP) n = CANDCAP;
    uint32_t base = cnt[b];
    uint32_t kn = PRE - base;
    for (uint32_t i = threadIdx.x; i < n; i += 256) s[i] = cand[(size_t)b * CANDCAP + i];
    __syncthreads();
    for (uint32_t i = threadIdx.x; i < n; i += 256) {
        u64 k = s[i];
        uint32_t r = 0;
        for (uint32_t j = 0; j < n; ++j) r += (s[j] > k) ? 1u : 0u;
        if (r < kn) selk[(size_t)b * PRE + base + r] = k;
    }
}

// 4) fused rank+scatter: block = 64 keys x 4 col-quarter threads; full 4096-key item
//    tile in LDS (32KB). Thread (key,q) counts greater keys over cols {8j+2q, 8j+2q+1}
//    via ds_read_b128 (4 distinct banks x 16-lane broadcast per wave-step: conflict-free).
//    4-lane shfl_xor reduce -> exact rank -> scatter sidx/ssc/bf in-block. No atomics.
__global__ void __launch_bounds__(256) k_rankscatter(const u64* __restrict__ selk,
                                                     const float* __restrict__ box,
                                                     int* __restrict__ sidx,
                                                     float* __restrict__ ssc,
                                                     float* __restrict__ bf) {
    const int bpi = PRE / RS_KPB;   // 64 blocks per item
    int b = blockIdx.x / bpi;
    int c = blockIdx.x % bpi;
    const u64* sk = selk + (size_t)b * PRE;
    __shared__ u64 tile[PRE];
    for (int i = threadIdx.x; i < PRE; i += 256) tile[i] = sk[i];
    __syncthreads();
    u64 myk = tile[c * RS_KPB + (threadIdx.x >> 2)];
    int q = threadIdx.x & 3;
    const ulonglong2* t2 = (const ulonglong2*)tile;
    int cnt = 0;
#pragma unroll 8
    for (int j = 0; j < PRE / 8; ++j) {
        ulonglong2 w = t2[4 * j + q];
        cnt += (w.x > myk) ? 1 : 0;
        cnt += (w.y > myk) ? 1 : 0;
    }
    cnt += __shfl_xor(cnt, 1, 64);
    cnt += __shfl_xor(cnt, 2, 64);
    if (q == 0) {
        int r = cnt;   // exact descending rank (keys distinct)
        int n = (int)(~(uint32_t)(myk & 0xFFFFFFFFull));
        float sc = u2f((uint32_t)(myk >> 32));
        sidx[b * PRE + r] = n;
        ssc[b * PRE + r] = sc;
        const float* bp = box + ((size_t)b * NN + n) * 7;
        float x = bp[0], y = bp[1], dx = bp[3], dy = bp[4];
        float* bfb = bf + (size_t)b * 5 * PRE;
        bfb[0 * PRE + r] = x - dx * 0.5f;
        bfb[1 * PRE + r] = x + dx * 0.5f;
        bfb[2 * PRE + r] = y - dy * 0.5f;
        bfb[3 * PRE + r] = y + dy * 0.5f;
        bfb[4 * PRE + r] = dx * dy;
    }
}

// 5) suppression rows [0,ROWS_END) x cols [0, WORDS*64): one wave per row,
//    word w = __ballot over lanes at j = w*64+lane (coalesced bf reads).
template<int ROWS_END, int WORDS, bool CHECK_FLAG>
__global__ void k_iou_t(const float* __restrict__ bf, u64* __restrict__ sup,
                        const uint32_t* __restrict__ flag) {
    const int bpi = ROWS_END / 4;            // blocks per item (4 waves/block)
    int b = blockIdx.x / bpi;
    if (CHECK_FLAG && flag[b]) return;
    int wave = threadIdx.x >> 6;
    int lane = threadIdx.x & 63;
    int i = (blockIdx.x % bpi) * 4 + wave;
    const float* bfb = bf + (size_t)b * 5 * PRE;
    float x1 = bfb[0 * PRE + i], x2 = bfb[1 * PRE + i];
    float y1 = bfb[2 * PRE + i], y2 = bfb[3 * PRE + i];
    float ar = bfb[4 * PRE + i];
    u64 myword = 0;
    for (int jw = 0; jw < WORDS; ++jw) {
        int j = jw * 64 + lane;
        float jx1 = bfb[0 * PRE + j], jx2 = bfb[1 * PRE + j];
        float jy1 = bfb[2 * PRE + j], jy2 = bfb[3 * PRE + j];
        float jar = bfb[4 * PRE + j];
        float ix = fminf(x2, jx2) - fmaxf(x1, jx1);
        ix = fmaxf(ix, 0.0f);
        float iy = fminf(y2, jy2) - fmaxf(y1, jy1);
        iy = fmaxf(iy, 0.0f);
        float inter = __fmul_rn(ix, iy);            // block FMA contraction (match np rounding)
        float uni = (ar + jar) - inter;
        float iou = inter / fmaxf(uni, 1e-6f);
        u64 bal = __ballot((iou > TH) && (j > i));
        if (jw == lane) myword = bal;
    }
    if (lane < WORDS) sup[((size_t)b * PRE + i) * 64 + lane] = myword;
}

__device__ __forceinline__ uint32_t kept_count(u64 removed, int words, int lane) {
    int v = (lane < words) ? __popcll(~removed) : 0;
#pragma unroll
    for (int off = 32; off > 0; off >>= 1) v += __shfl_xor(v, off, 64);
    return (uint32_t)v;
}

// 6) greedy scan rows [0,END): 1 wave/item, lane w owns removed-word w.
//    Decision broadcast via __ballot (pure VALU/vcc). Unconditional loads keep the
//    16+16-row double-buffer in VGPRs. Early exit once POST kept rows finalized.
template<int END, int WORDS, bool CHECK_FLAG>
__global__ void __launch_bounds__(64, 1) k_scan_t(const u64* __restrict__ sup,
                                                  u64* __restrict__ keepm,
                                                  uint32_t* __restrict__ flag) {
    const int CH = 16;
    int b = blockIdx.x;
    int lane = threadIdx.x;   // 64 threads = 1 wave
    if (CHECK_FLAG && flag[b]) return;
    u64 removed = 0;
    const u64* sb = sup + (size_t)b * PRE * 64;

    u64 bufA[CH], bufB[CH];
#pragma unroll
    for (int p = 0; p < CH; ++p) bufA[p] = sb[(size_t)p * 64 + lane];

    bool fin = false;
    int S = END;
    for (int g = 0; g < END; g += 2 * CH) {
#pragma unroll
        for (int p = 0; p < CH; ++p) bufB[p] = sb[(size_t)(g + CH + p) * 64 + lane];
#pragma unroll
        for (int p = 0; p < CH; ++p) {
            int i = g + p;
            u64 bal = __ballot(((removed >> (i & 63)) & 1ull) != 0ull);
            u64 rmmask = ((bal >> (i >> 6)) & 1ull) ? 0ull : ~0ull;
            removed |= bufA[p] & rmmask;
        }
        if (g + 2 * CH < END) {
#pragma unroll
            for (int p = 0; p < CH; ++p) bufA[p] = sb[(size_t)(g + 2 * CH + p) * 64 + lane];
        }
#pragma unroll
        for (int p = 0; p < CH; ++p) {
            int i = g + CH + p;
            u64 bal = __ballot(((removed >> (i & 63)) & 1ull) != 0ull);
            u64 rmmask = ((bal >> (i >> 6)) & 1ull) ? 0ull : ~0ull;
            removed |= bufB[p] & rmmask;
        }
        int done = g + 2 * CH;
        if ((done & 63) == 0 && done >= POST + 64) {   // first possible exit: 576 rows
            uint32_t kept = kept_count(removed, done >> 6, lane);
            if (kept >= POST) { S = done; fin = true; break; }
        }
    }

    if (fin || END == PRE) {
        int words = S >> 6;
        keepm[b * 64 + lane] = (lane < words) ? ~removed : 0ull;
        if (lane == 0) flag[b] = 1;
    } else {
        if (lane == 0) flag[b] = 0;   // phase B does full recompute + rescan
    }
}

// 7) outputs: destination = position in argsort(where(keep, rank, PRE))
__global__ void __launch_bounds__(512) k_out(const u64* __restrict__ keepm,
                                             const int* __restrict__ sidx,
                                             const float* __restrict__ ssc,
                                             const float* __restrict__ box,
                                             const float* __restrict__ cls,
                                             float* __restrict__ out) {
    int b = blockIdx.x;
    __shared__ uint32_t wpre[65];
    const u64* km = keepm + b * 64;
    if (threadIdx.x == 0) {
        uint32_t c = 0;
        for (int w = 0; w < 64; ++w) { wpre[w] = c; c += (uint32_t)__popcll(km[w]); }
        wpre[64] = c;
    }
    __syncthreads();
    uint32_t nkeep = wpre[64];
    for (int r = threadIdx.x; r < PRE; r += blockDim.x) {
        int w = r >> 6, bit = r & 63;
        u64 word = km[w];
        bool kept = (word >> bit) & 1ull;
        u64 mask = bit ? ((1ull << bit) - 1ull) : 0ull;
        uint32_t before = wpre[w] + (uint32_t)__popcll(word & mask);
        uint32_t d = kept ? before : (nkeep + (uint32_t)r - before);
        if (d < POST) {
            float* ro = out + ((size_t)b * POST + d) * 7;
            float* so = out + (size_t)BB * POST * 7 + b * POST + d;
            float* lo = out + (size_t)BB * POST * 8 + b * POST + d;
            if (kept) {
                int n = sidx[b * PRE + r];
                const float* bp = box + ((size_t)b * NN + n) * 7;
#pragma unroll
                for (int t = 0; t < 7; ++t) ro[t] = bp[t];
                *so = ssc[b * PRE + r];
                const float* cp = cls + ((size_t)b * NN + n) * CC;
                float c0 = cp[0], c1 = cp[1], c2 = cp[2];
                int lbl = 0; float bst = c0;
                if (c1 > bst) { bst = c1; lbl = 1; }
                if (c2 > bst) { lbl = 2; }
                *lo = (float)(lbl + 1);
            } else {
#pragma unroll
                for (int t = 0; t < 7; ++t) ro[t] = 0.0f;
                *so = 0.0f;
                *lo = 1.0f;
            }
        }
    }
}

extern "C" void kernel_launch(void* const* d_in, const int* in_sizes, int n_in,
                              void* d_out, int out_size, void* d_ws, size_t ws_size,
                              hipStream_t stream) {
    const float* cls = (const float*)d_in[0];   // (4, 32768, 3)
    const float* box = (const float*)d_in[1];   // (4, 32768, 7)
    float* out = (float*)d_out;                 // 18432 floats

    char* ws = (char*)d_ws;
    const size_t MB = 1024 * 1024;
    // sup occupies [0, 8MB); hist/cand/selk alias inside it.
    // Phase-A iou writes only sup rows<768 words<12 => per item bytes [b*2MB, b*2MB+393KB):
    //   item0 hits [0,393K)   - nothing lives there
    //   item1 hits [2M,2.39M) - hist_c/cand (dead after k_final)
    //   item2 hits [4M,4.39M) - nothing
    //   item3 hits [6M,6.39M) - nothing
    // hist_f (1MB) and selk (3MB) are outside all written ranges; selk dead after
    // k_rankscatter anyway. Phase-B full iou rewrites all 8MB - everything aliased is dead.
    size_t OFF_SUP   = 0;
    size_t OFF_HISTF = 1 * MB;                   // 1 MB  (4 x 65536 x 4)
    size_t OFF_HISTC = 2 * MB;                   // 4 KB  (4 x 256 x 4)
    size_t OFF_CAND  = 2 * MB + 4096;            // 128 KB (4 x 4096 x 8)
    size_t OFF_SELK  = 3 * MB;                   // 128 KB
    size_t OFF_BF    = 8 * MB;                   // 320 KB
    size_t OFF_SIDX  = OFF_BF + (size_t)BB * 5 * PRE * 4;
    size_t OFF_SSC   = OFF_SIDX + (size_t)BB * PRE * 4;
    size_t OFF_KEEP  = OFF_SSC + (size_t)BB * PRE * 4;
    size_t OFF_SCAL  = OFF_KEEP + (size_t)BB * 64 * 8;   // cnt[4],ccnt[4],flag[4],pad

    u64*      sup    = (u64*)(ws + OFF_SUP);
    uint32_t* hist_f = (uint32_t*)(ws + OFF_HISTF);
    uint32_t* hist_c = (uint32_t*)(ws + OFF_HISTC);
    u64*      cand   = (u64*)(ws + OFF_CAND);
    u64*      selk   = (u64*)(ws + OFF_SELK);
    float*    bf     = (float*)(ws + OFF_BF);
    int*      sidx   = (int*)(ws + OFF_SIDX);
    float*    ssc    = (float*)(ws + OFF_SSC);
    u64*      keepm  = (u64*)(ws + OFF_KEEP);
    uint32_t* scal   = (uint32_t*)(ws + OFF_SCAL);
    uint32_t* cnt    = scal;
    uint32_t* ccnt   = scal + 4;
    uint32_t* flag   = scal + 8;

    // zero hist_f + hist_c (contiguous 1MB+4KB) and counters
    int n16 = (int)((MB + 4096) / 16);
    k_zero<<<(n16 + 255) / 256, 256, 0, stream>>>((uint4*)(ws + OFF_HISTF), scal, n16);
    k_hist<<<(BB * NN) / 256, 256, 0, stream>>>(cls, hist_f, hist_c);
    k_collect<<<(BB * NN) / 256, 256, 0, stream>>>(cls, hist_c, hist_f, cnt, ccnt, selk, cand);
    k_final<<<BB, 256, 0, stream>>>(cand, ccnt, cnt, selk);
    k_rankscatter<<<BB * (PRE / RS_KPB), 256, 0, stream>>>(selk, box, sidx, ssc, bf);

    // Phase A: 768x768 sub-matrix (12 words/row) + early-exit scan
    k_iou_t<ROWS_A, ROWS_A / 64, false><<<(ROWS_A / 4) * BB, 256, 0, stream>>>(bf, sup, flag);
    k_scan_t<ROWS_A, ROWS_A / 64, false><<<BB, 64, 0, stream>>>(sup, keepm, flag);
    // Phase B (fallback, per-item no-op when flag==1): full 4096x4096 matrix + full rescan
    k_iou_t<PRE, 64, true><<<(PRE / 4) * BB, 256, 0, stream>>>(bf, sup, flag);
    k_scan_t<PRE, 64, true><<<BB, 64, 0, stream>>>(sup, keepm, flag);

    k_out<<<BB, 512, 0, stream>>>(keepm, sidx, ssc, box, cls, out);
}

// Round 9
// 99.812 us; speedup vs baseline: 20.7062x; 1.0398x over previous
//
#include <hip/hip_runtime.h>
#include <stdint.h>

typedef unsigned long long u64;

#define BB 4
#define NN 32768
#define CC 3
#define PRE 4096
#define POST 512
#define TH 0.7f
#define ROWS_A 768    // phase-A rows AND cols (12 words); early exit expected ~576-768
#define CANDCAP 4096
#define RS_TILE 6144  // union tile cap (cnt + ccnt), 48KB LDS
#define RS_BPI 96     // rankscatter blocks per item (covers RS_TILE keys)

__device__ __forceinline__ uint32_t f2u(float f) {
    uint32_t b = __float_as_uint(f);
    return (b & 0x80000000u) ? ~b : (b | 0x80000000u);
}
__device__ __forceinline__ float u2f(uint32_t u) {
    uint32_t b = (u & 0x80000000u) ? (u & 0x7FFFFFFFu) : ~u;
    return __uint_as_float(b);
}
__device__ __forceinline__ float score3(const float* p) {
    return fmaxf(fmaxf(p[0], p[1]), p[2]);
}

// 0) zero hist region (uint4 stride) + scalar counters
__global__ void k_zero(uint4* __restrict__ histreg, uint32_t* __restrict__ scal, int n16) {
    int gid = blockIdx.x * blockDim.x + threadIdx.x;
    if (gid < n16) histreg[gid] = make_uint4(0, 0, 0, 0);
    if (gid < 16) scal[gid] = 0;
}

// 1) 2-level histogram of top-16 key bits (keys recomputed, never materialized).
//    key = (orderable(score)<<32) | ~index  (distinct keys => exact top_k tie-break)
__global__ void k_hist(const float* __restrict__ cls,
                       uint32_t* __restrict__ hist_f, uint32_t* __restrict__ hist_c) {
    __shared__ uint32_t lc[256];
    lc[threadIdx.x] = 0;
    __syncthreads();
    int gid = blockIdx.x * blockDim.x + threadIdx.x;   // 512 blocks x 256; block spans one item
    int b = gid >> 15;
    uint32_t p16 = f2u(score3(cls + (size_t)gid * CC)) >> 16;
    atomicAdd(&hist_f[((uint32_t)b << 16) + p16], 1u);
    atomicAdd(&lc[p16 >> 8], 1u);
    __syncthreads();
    uint32_t v = lc[threadIdx.x];
    if (v) atomicAdd(&hist_c[((uint32_t)b << 8) + threadIdx.x], v);
}

// 2) collect (fused threshold-choose): block re-derives the 16-bit threshold prefix via
//    two parallel suffix-scans, then: definite winners (p16 > pb) -> block-aggregated
//    compaction into selk (1 atomic/block); boundary bin (p16 == pb) -> cand list.
__global__ void __launch_bounds__(256) k_collect(const float* __restrict__ cls,
                                                 const uint32_t* __restrict__ hist_c,
                                                 const uint32_t* __restrict__ hist_f,
                                                 uint32_t* __restrict__ cnt,
                                                 uint32_t* __restrict__ ccnt,
                                                 u64* __restrict__ selk, u64* __restrict__ cand) {
    int tid = threadIdx.x;
    int gid = blockIdx.x * 256 + tid;
    int b = gid >> 15;
    __shared__ uint32_t pref[256];
    __shared__ uint32_t s_selc, s_remc, s_pb;

    // coarse suffix-scan: thread t owns coarse bin (255 - t)
    uint32_t v = hist_c[((uint32_t)b << 8) + 255 - tid];
    pref[tid] = v;
    __syncthreads();
    for (int off = 1; off < 256; off <<= 1) {
        uint32_t x = (tid >= off) ? pref[tid - off] : 0;
        __syncthreads();
        pref[tid] += x;
        __syncthreads();
    }
    {
        uint32_t after = pref[tid], before = after - v;
        if (before < PRE && PRE <= after) { s_selc = 255 - tid; s_remc = PRE - before; }
    }
    __syncthreads();
    uint32_t selc = s_selc, remc = s_remc;
    // fine suffix-scan within chosen coarse bin
    uint32_t v2 = hist_f[((uint32_t)b << 16) + (selc << 8) + 255 - tid];
    __syncthreads();
    pref[tid] = v2;
    __syncthreads();
    for (int off = 1; off < 256; off <<= 1) {
        uint32_t x = (tid >= off) ? pref[tid - off] : 0;
        __syncthreads();
        pref[tid] += x;
        __syncthreads();
    }
    {
        uint32_t after = pref[tid], before = after - v2;
        if (before < remc && remc <= after) s_pb = (selc << 8) | (uint32_t)(255 - tid);
    }
    __syncthreads();
    uint32_t pb = s_pb;

    // recompute key for my element
    u64 k = ((u64)f2u(score3(cls + (size_t)gid * CC)) << 32)
          | (uint32_t)(~(uint32_t)(gid & (NN - 1)));
    uint32_t p16 = (uint32_t)(k >> 48);
    bool def = p16 > pb;
    u64 mask = __ballot(def);
    int lane = tid & 63;
    int wave = tid >> 6;
    __shared__ uint32_t wtot[4], wbase[4], blockbase;
    uint32_t rank = lane ? (uint32_t)__popcll(mask & ((~0ull) >> (64 - lane))) : 0u;
    if (lane == 0) wtot[wave] = (uint32_t)__popcll(mask);
    __syncthreads();
    if (tid == 0) {
        uint32_t t = 0;
        for (int w = 0; w < 4; ++w) { wbase[w] = t; t += wtot[w]; }
        blockbase = atomicAdd(&cnt[b], t);
    }
    __syncthreads();
    if (def) {
        selk[(size_t)b * PRE + blockbase + wbase[wave] + rank] = k;
    } else if (p16 == pb) {
        uint32_t pos = atomicAdd(&ccnt[b], 1u);
        if (pos < CANDCAP) cand[(size_t)b * CANDCAP + pos] = k;
    }
}

// 3) fused union rank+scatter: tile = selk[0..cnt) ++ cand[0..ccnt) (all keys p16>=pb;
//    every union key beats every non-union key => union rank == global rank).
//    Block = 64 keys x 4 col-quarter threads; full union tile in LDS; ds_read_b128
//    broadcast reads; 2-step shfl reduce -> exact rank; scatter iff r < PRE. No atomics.
__global__ void __launch_bounds__(256) k_rankscatter(const u64* __restrict__ selk,
                                                     const u64* __restrict__ cand,
                                                     const uint32_t* __restrict__ cnt,
                                                     const uint32_t* __restrict__ ccnt,
                                                     const float* __restrict__ box,
                                                     int* __restrict__ sidx,
                                                     float* __restrict__ ssc,
                                                     float* __restrict__ bf) {
    int b = blockIdx.x / RS_BPI;
    int c = blockIdx.x % RS_BPI;
    uint32_t base = cnt[b];
    uint32_t cc = ccnt[b]; if (cc > CANDCAP) cc = CANDCAP;
    uint32_t m = base + cc; if (m > RS_TILE) m = RS_TILE;
    if ((uint32_t)(c * 64) >= m) return;
    __shared__ u64 tile[RS_TILE];
    uint32_t mp = (m + 7) & ~7u;   // pad to 8; pad value 0 never counts (keys > 0)
    for (uint32_t i = threadIdx.x; i < mp; i += 256)
        tile[i] = (i < base) ? selk[(size_t)b * PRE + i]
                : (i < m)    ? cand[(size_t)b * CANDCAP + (i - base)] : 0ull;
    __syncthreads();
    uint32_t k = c * 64 + (threadIdx.x >> 2);
    u64 myk = tile[(k < m) ? k : 0];
    int q = threadIdx.x & 3;
    const ulonglong2* t2 = (const ulonglong2*)tile;
    int cn = 0;
#pragma unroll 8
    for (uint32_t j = 0; j < mp / 8; ++j) {
        ulonglong2 w = t2[4 * j + q];
        cn += (w.x > myk) ? 1 : 0;
        cn += (w.y > myk) ? 1 : 0;
    }
    cn += __shfl_xor(cn, 1, 64);
    cn += __shfl_xor(cn, 2, 64);
    if (q == 0 && k < m && cn < PRE) {
        int r = cn;   // exact global descending rank (keys distinct)
        int n = (int)(~(uint32_t)(myk & 0xFFFFFFFFull));
        float sc = u2f((uint32_t)(myk >> 32));
        sidx[b * PRE + r] = n;
        ssc[b * PRE + r] = sc;
        const float* bp = box + ((size_t)b * NN + n) * 7;
        float x = bp[0], y = bp[1], dx = bp[3], dy = bp[4];
        float* bfb = bf + (size_t)b * 5 * PRE;
        bfb[0 * PRE + r] = x - dx * 0.5f;
        bfb[1 * PRE + r] = x + dx * 0.5f;
        bfb[2 * PRE + r] = y - dy * 0.5f;
        bfb[3 * PRE + r] = y + dy * 0.5f;
        bfb[4 * PRE + r] = dx * dy;
    }
}

// 4) suppression rows [0,ROWS_END) x cols [0, WORDS*64): one wave per row,
//    word w = __ballot over lanes at j = w*64+lane (coalesced bf reads).
template<int ROWS_END, int WORDS>
__global__ void k_iou_t(const float* __restrict__ bf, u64* __restrict__ sup) {
    const int bpi = ROWS_END / 4;            // blocks per item (4 waves/block)
    int b = blockIdx.x / bpi;
    int wave = threadIdx.x >> 6;
    int lane = threadIdx.x & 63;
    int i = (blockIdx.x % bpi) * 4 + wave;
    const float* bfb = bf + (size_t)b * 5 * PRE;
    float x1 = bfb[0 * PRE + i], x2 = bfb[1 * PRE + i];
    float y1 = bfb[2 * PRE + i], y2 = bfb[3 * PRE + i];
    float ar = bfb[4 * PRE + i];
    u64 myword = 0;
    for (int jw = 0; jw < WORDS; ++jw) {
        int j = jw * 64 + lane;
        float jx1 = bfb[0 * PRE + j], jx2 = bfb[1 * PRE + j];
        float jy1 = bfb[2 * PRE + j], jy2 = bfb[3 * PRE + j];
        float jar = bfb[4 * PRE + j];
        float ix = fminf(x2, jx2) - fmaxf(x1, jx1);
        ix = fmaxf(ix, 0.0f);
        float iy = fminf(y2, jy2) - fmaxf(y1, jy1);
        iy = fmaxf(iy, 0.0f);
        float inter = __fmul_rn(ix, iy);            // block FMA contraction (match np rounding)
        float uni = (ar + jar) - inter;
        float iou = inter / fmaxf(uni, 1e-6f);
        u64 bal = __ballot((iou > TH) && (j > i));
        if (jw == lane) myword = bal;
    }
    if (lane < WORDS) sup[((size_t)b * PRE + i) * 64 + lane] = myword;
}

__device__ __forceinline__ uint32_t kept_count(u64 removed, int words, int lane) {
    int v = (lane < words) ? __popcll(~removed) : 0;
#pragma unroll
    for (int off = 32; off > 0; off >>= 1) v += __shfl_xor(v, off, 64);
    return (uint32_t)v;
}

// 5) greedy scan rows [0,END): 1 wave/item, lane w owns removed-word w.
//    Decision broadcast via __ballot (pure VALU/vcc). Unconditional loads keep the
//    16+16-row double-buffer in VGPRs. Early exit once POST kept rows finalized.
//    flag=1 + truncated keepm on success; flag=0 -> k_finalout serial fallback.
template<int END, int WORDS>
__global__ void __launch_bounds__(64, 1) k_scan_t(const u64* __restrict__ sup,
                                                  u64* __restrict__ keepm,
                                                  uint32_t* __restrict__ flag) {
    const int CH = 16;
    int b = blockIdx.x;
    int lane = threadIdx.x;   // 64 threads = 1 wave
    u64 removed = 0;
    const u64* sb = sup + (size_t)b * PRE * 64;

    u64 bufA[CH], bufB[CH];
#pragma unroll
    for (int p = 0; p < CH; ++p) bufA[p] = sb[(size_t)p * 64 + lane];

    bool fin = false;
    int S = END;
    for (int g = 0; g < END; g += 2 * CH) {
#pragma unroll
        for (int p = 0; p < CH; ++p) bufB[p] = sb[(size_t)(g + CH + p) * 64 + lane];
#pragma unroll
        for (int p = 0; p < CH; ++p) {
            int i = g + p;
            u64 bal = __ballot(((removed >> (i & 63)) & 1ull) != 0ull);
            u64 rmmask = ((bal >> (i >> 6)) & 1ull) ? 0ull : ~0ull;
            removed |= bufA[p] & rmmask;
        }
        if (g + 2 * CH < END) {
#pragma unroll
            for (int p = 0; p < CH; ++p) bufA[p] = sb[(size_t)(g + 2 * CH + p) * 64 + lane];
        }
#pragma unroll
        for (int p = 0; p < CH; ++p) {
            int i = g + CH + p;
            u64 bal = __ballot(((removed >> (i & 63)) & 1ull) != 0ull);
            u64 rmmask = ((bal >> (i >> 6)) & 1ull) ? 0ull : ~0ull;
            removed |= bufB[p] & rmmask;
        }
        int done = g + 2 * CH;
        if ((done & 63) == 0 && done >= POST + 64) {   // first possible exit: 576 rows
            uint32_t kept = kept_count(removed, done >> 6, lane);
            if (kept >= POST) { S = done; fin = true; break; }
        }
    }

    if (fin) {
        int words = S >> 6;
        keepm[b * 64 + lane] = (lane < words) ? ~removed : 0ull;
        if (lane == 0) flag[b] = 1;
    } else {
        if (lane == 0) flag[b] = 0;
    }
}

// 6) fused fallback + output. Per item: if flag==0, serial full 4096-row NMS in-block
//    (exact reference semantics; ~0.4ms, never triggers on expected data). Then output:
//    destination = position in argsort(where(keep, rank, PRE)).
__global__ void __launch_bounds__(512) k_finalout(const u64* __restrict__ keepm,
                                                  const uint32_t* __restrict__ flag,
                                                  const int* __restrict__ sidx,
                                                  const float* __restrict__ ssc,
                                                  const float* __restrict__ box,
                                                  const float* __restrict__ cls,
                                                  const float* __restrict__ bf,
                                                  float* __restrict__ out) {
    int b = blockIdx.x;
    int tid = threadIdx.x;
    __shared__ u64 km[64];
    __shared__ uint32_t wpre[65];
    const float* bfb = bf + (size_t)b * 5 * PRE;

    if (flag[b]) {
        if (tid < 64) km[tid] = keepm[b * 64 + tid];
        __syncthreads();
    } else {
        // serial greedy fallback over all PRE ranked boxes
        if (tid < 64) km[tid] = ~0ull;
        __syncthreads();
        for (int i = 0; i < PRE - 1; ++i) {
            if ((km[i >> 6] >> (i & 63)) & 1ull) {
                float x1 = bfb[0 * PRE + i], x2 = bfb[1 * PRE + i];
                float y1 = bfb[2 * PRE + i], y2 = bfb[3 * PRE + i];
                float ar = bfb[4 * PRE + i];
                for (int j = i + 1 + tid; j < PRE; j += 512) {
                    float ix = fminf(x2, bfb[1 * PRE + j]) - fmaxf(x1, bfb[0 * PRE + j]);
                    ix = fmaxf(ix, 0.0f);
                    float iy = fminf(y2, bfb[3 * PRE + j]) - fmaxf(y1, bfb[2 * PRE + j]);
                    iy = fmaxf(iy, 0.0f);
                    float inter = __fmul_rn(ix, iy);
                    float uni = (ar + bfb[4 * PRE + j]) - inter;
                    float iou = inter / fmaxf(uni, 1e-6f);
                    if (iou > TH) atomicAnd(&km[j >> 6], ~(1ull << (j & 63)));
                }
            }
            __syncthreads();
        }
    }

    if (tid == 0) {
        uint32_t c = 0;
        for (int w = 0; w < 64; ++w) { wpre[w] = c; c += (uint32_t)__popcll(km[w]); }
        wpre[64] = c;
    }
    __syncthreads();
    uint32_t nkeep = wpre[64];
    for (int r = tid; r < PRE; r += 512) {
        int w = r >> 6, bit = r & 63;
        u64 word = km[w];
        bool kept = (word >> bit) & 1ull;
        u64 mask = bit ? ((1ull << bit) - 1ull) : 0ull;
        uint32_t before = wpre[w] + (uint32_t)__popcll(word & mask);
        uint32_t d = kept ? before : (nkeep + (uint32_t)r - before);
        if (d < POST) {
            float* ro = out + ((size_t)b * POST + d) * 7;
            float* so = out + (size_t)BB * POST * 7 + b * POST + d;
            float* lo = out + (size_t)BB * POST * 8 + b * POST + d;
            if (kept) {
                int n = sidx[b * PRE + r];
                const float* bp = box + ((size_t)b * NN + n) * 7;
#pragma unroll
                for (int t = 0; t < 7; ++t) ro[t] = bp[t];
                *so = ssc[b * PRE + r];
                const float* cp = cls + ((size_t)b * NN + n) * CC;
                float c0 = cp[0], c1 = cp[1], c2 = cp[2];
                int lbl = 0; float bst = c0;
                if (c1 > bst) { bst = c1; lbl = 1; }
                if (c2 > bst) { lbl = 2; }
                *lo = (float)(lbl + 1);
            } else {
#pragma unroll
                for (int t = 0; t < 7; ++t) ro[t] = 0.0f;
                *so = 0.0f;
                *lo = 1.0f;
            }
        }
    }
}

extern "C" void kernel_launch(void* const* d_in, const int* in_sizes, int n_in,
                              void* d_out, int out_size, void* d_ws, size_t ws_size,
                              hipStream_t stream) {
    const float* cls = (const float*)d_in[0];   // (4, 32768, 3)
    const float* box = (const float*)d_in[1];   // (4, 32768, 7)
    float* out = (float*)d_out;                 // 18432 floats

    char* ws = (char*)d_ws;
    const size_t MB = 1024 * 1024;
    // sup occupies [0, 8MB); hist/cand/selk alias inside it.
    // Phase-A iou writes item b bytes [b*2MB, b*2MB + 384KB):
    //   item0 [0,384K): empty; item1 [2M,2.38M): hist_c+cand (dead after k_rankscatter);
    //   item2/3: empty. hist_f (1MB) and selk (3M..3.125M) untouched (and dead by then).
    size_t OFF_SUP   = 0;
    size_t OFF_HISTF = 1 * MB;                   // 1 MB  (4 x 65536 x 4)
    size_t OFF_HISTC = 2 * MB;                   // 4 KB  (4 x 256 x 4)
    size_t OFF_CAND  = 2 * MB + 4096;            // 128 KB (4 x 4096 x 8)
    size_t OFF_SELK  = 3 * MB;                   // 128 KB
    size_t OFF_BF    = 8 * MB;                   // 320 KB
    size_t OFF_SIDX  = OFF_BF + (size_t)BB * 5 * PRE * 4;
    size_t OFF_SSC   = OFF_SIDX + (size_t)BB * PRE * 4;
    size_t OFF_KEEP  = OFF_SSC + (size_t)BB * PRE * 4;
    size_t OFF_SCAL  = OFF_KEEP + (size_t)BB * 64 * 8;   // cnt[4],ccnt[4],flag[4],pad

    u64*      sup    = (u64*)(ws + OFF_SUP);
    uint32_t* hist_f = (uint32_t*)(ws + OFF_HISTF);
    uint32_t* hist_c = (uint32_t*)(ws + OFF_HISTC);
    u64*      cand   = (u64*)(ws + OFF_CAND);
    u64*      selk   = (u64*)(ws + OFF_SELK);
    float*    bf     = (float*)(ws + OFF_BF);
    int*      sidx   = (int*)(ws + OFF_SIDX);
    float*    ssc    = (float*)(ws + OFF_SSC);
    u64*      keepm  = (u64*)(ws + OFF_KEEP);
    uint32_t* scal   = (uint32_t*)(ws + OFF_SCAL);
    uint32_t* cnt    = scal;
    uint32_t* ccnt   = scal + 4;
    uint32_t* flag   = scal + 8;

    // 7-launch chain (each depends on the previous):
    int n16 = (int)((MB + 4096) / 16);
    k_zero<<<(n16 + 255) / 256, 256, 0, stream>>>((uint4*)(ws + OFF_HISTF), scal, n16);
    k_hist<<<(BB * NN) / 256, 256, 0, stream>>>(cls, hist_f, hist_c);
    k_collect<<<(BB * NN) / 256, 256, 0, stream>>>(cls, hist_c, hist_f, cnt, ccnt, selk, cand);
    k_rankscatter<<<BB * RS_BPI, 256, 0, stream>>>(selk, cand, cnt, ccnt, box, sidx, ssc, bf);
    k_iou_t<ROWS_A, ROWS_A / 64><<<(ROWS_A / 4) * BB, 256, 0, stream>>>(bf, sup);
    k_scan_t<ROWS_A, ROWS_A / 64><<<BB, 64, 0, stream>>>(sup, keepm, flag);
    k_finalout<<<BB, 512, 0, stream>>>(keepm, flag, sidx, ssc, box, cls, bf, out);
}

// Round 10
// 86.985 us; speedup vs baseline: 23.7596x; 1.1475x over previous
//
#include <hip/hip_runtime.h>
#include <stdint.h>

typedef unsigned long long u64;

#define BB 4
#define NN 32768
#define CC 3
#define PRE 4096
#define POST 512
#define TH 0.7f
#define ROWS_A 768    // phase-A rows AND cols (12 words); kept>=512 within 768 expected
#define RW (ROWS_A / 64)
#define CANDCAP 4096
#define RS_TILE 6144  // union tile cap (cnt + ccnt), 48KB LDS
#define RS_BPI 96     // rankscatter blocks per item (covers RS_TILE keys)

__device__ __forceinline__ uint32_t f2u(float f) {
    uint32_t b = __float_as_uint(f);
    return (b & 0x80000000u) ? ~b : (b | 0x80000000u);
}
__device__ __forceinline__ float u2f(uint32_t u) {
    uint32_t b = (u & 0x80000000u) ? (u & 0x7FFFFFFFu) : ~u;
    return __uint_as_float(b);
}
__device__ __forceinline__ float score3(const float* p) {
    return fmaxf(fmaxf(p[0], p[1]), p[2]);
}

// 1) 2-level histogram of top-16 key bits (keys recomputed, never materialized).
//    Block 0 also zeroes the scalar counters (untouched by this kernel's atomics).
__global__ void k_hist(const float* __restrict__ cls,
                       uint32_t* __restrict__ hist_f, uint32_t* __restrict__ hist_c,
                       uint32_t* __restrict__ scal) {
    __shared__ uint32_t lc[256];
    lc[threadIdx.x] = 0;
    if (blockIdx.x == 0 && threadIdx.x < 16) scal[threadIdx.x] = 0;
    __syncthreads();
    int gid = blockIdx.x * blockDim.x + threadIdx.x;   // 512 blocks x 256; block spans one item
    int b = gid >> 15;
    uint32_t p16 = f2u(score3(cls + (size_t)gid * CC)) >> 16;
    atomicAdd(&hist_f[((uint32_t)b << 16) + p16], 1u);
    atomicAdd(&lc[p16 >> 8], 1u);
    __syncthreads();
    uint32_t v = lc[threadIdx.x];
    if (v) atomicAdd(&hist_c[((uint32_t)b << 8) + threadIdx.x], v);
}

// 2) collect (fused threshold-choose): block re-derives the 16-bit threshold prefix via
//    two parallel suffix-scans, then: definite winners (p16 > pb) -> block-aggregated
//    compaction into selk (1 atomic/block); boundary bin (p16 == pb) -> cand list.
__global__ void __launch_bounds__(256) k_collect(const float* __restrict__ cls,
                                                 const uint32_t* __restrict__ hist_c,
                                                 const uint32_t* __restrict__ hist_f,
                                                 uint32_t* __restrict__ cnt,
                                                 uint32_t* __restrict__ ccnt,
                                                 u64* __restrict__ selk, u64* __restrict__ cand) {
    int tid = threadIdx.x;
    int gid = blockIdx.x * 256 + tid;
    int b = gid >> 15;
    __shared__ uint32_t pref[256];
    __shared__ uint32_t s_selc, s_remc, s_pb;

    // coarse suffix-scan: thread t owns coarse bin (255 - t)
    uint32_t v = hist_c[((uint32_t)b << 8) + 255 - tid];
    pref[tid] = v;
    __syncthreads();
    for (int off = 1; off < 256; off <<= 1) {
        uint32_t x = (tid >= off) ? pref[tid - off] : 0;
        __syncthreads();
        pref[tid] += x;
        __syncthreads();
    }
    {
        uint32_t after = pref[tid], before = after - v;
        if (before < PRE && PRE <= after) { s_selc = 255 - tid; s_remc = PRE - before; }
    }
    __syncthreads();
    uint32_t selc = s_selc, remc = s_remc;
    // fine suffix-scan within chosen coarse bin
    uint32_t v2 = hist_f[((uint32_t)b << 16) + (selc << 8) + 255 - tid];
    __syncthreads();
    pref[tid] = v2;
    __syncthreads();
    for (int off = 1; off < 256; off <<= 1) {
        uint32_t x = (tid >= off) ? pref[tid - off] : 0;
        __syncthreads();
        pref[tid] += x;
        __syncthreads();
    }
    {
        uint32_t after = pref[tid], before = after - v2;
        if (before < remc && remc <= after) s_pb = (selc << 8) | (uint32_t)(255 - tid);
    }
    __syncthreads();
    uint32_t pb = s_pb;

    // recompute key for my element
    u64 k = ((u64)f2u(score3(cls + (size_t)gid * CC)) << 32)
          | (uint32_t)(~(uint32_t)(gid & (NN - 1)));
    uint32_t p16 = (uint32_t)(k >> 48);
    bool def = p16 > pb;
    u64 mask = __ballot(def);
    int lane = tid & 63;
    int wave = tid >> 6;
    __shared__ uint32_t wtot[4], wbase[4], blockbase;
    uint32_t rank = lane ? (uint32_t)__popcll(mask & ((~0ull) >> (64 - lane))) : 0u;
    if (lane == 0) wtot[wave] = (uint32_t)__popcll(mask);
    __syncthreads();
    if (tid == 0) {
        uint32_t t = 0;
        for (int w = 0; w < 4; ++w) { wbase[w] = t; t += wtot[w]; }
        blockbase = atomicAdd(&cnt[b], t);
    }
    __syncthreads();
    if (def) {
        selk[(size_t)b * PRE + blockbase + wbase[wave] + rank] = k;
    } else if (p16 == pb) {
        uint32_t pos = atomicAdd(&ccnt[b], 1u);
        if (pos < CANDCAP) cand[(size_t)b * CANDCAP + pos] = k;
    }
}

// 3) fused union rank+scatter: tile = selk[0..cnt) ++ cand[0..ccnt); union keys (p16>=pb)
//    all beat non-union keys => union rank == global rank. Scatter iff rank < PRE.
__global__ void __launch_bounds__(256) k_rankscatter(const u64* __restrict__ selk,
                                                     const u64* __restrict__ cand,
                                                     const uint32_t* __restrict__ cnt,
                                                     const uint32_t* __restrict__ ccnt,
                                                     const float* __restrict__ box,
                                                     int* __restrict__ sidx,
                                                     float* __restrict__ ssc,
                                                     float* __restrict__ bf) {
    int b = blockIdx.x / RS_BPI;
    int c = blockIdx.x % RS_BPI;
    uint32_t base = cnt[b];
    uint32_t cc = ccnt[b]; if (cc > CANDCAP) cc = CANDCAP;
    uint32_t m = base + cc; if (m > RS_TILE) m = RS_TILE;
    if ((uint32_t)(c * 64) >= m) return;
    __shared__ u64 tile[RS_TILE];
    uint32_t mp = (m + 7) & ~7u;   // pad to 8; pad value 0 never counts (keys > 0)
    for (uint32_t i = threadIdx.x; i < mp; i += 256)
        tile[i] = (i < base) ? selk[(size_t)b * PRE + i]
                : (i < m)    ? cand[(size_t)b * CANDCAP + (i - base)] : 0ull;
    __syncthreads();
    uint32_t k = c * 64 + (threadIdx.x >> 2);
    u64 myk = tile[(k < m) ? k : 0];
    int q = threadIdx.x & 3;
    const ulonglong2* t2 = (const ulonglong2*)tile;
    int cn = 0;
#pragma unroll 8
    for (uint32_t j = 0; j < mp / 8; ++j) {
        ulonglong2 w = t2[4 * j + q];
        cn += (w.x > myk) ? 1 : 0;
        cn += (w.y > myk) ? 1 : 0;
    }
    cn += __shfl_xor(cn, 1, 64);
    cn += __shfl_xor(cn, 2, 64);
    if (q == 0 && k < m && cn < PRE) {
        int r = cn;   // exact global descending rank (keys distinct)
        int n = (int)(~(uint32_t)(myk & 0xFFFFFFFFull));
        float sc = u2f((uint32_t)(myk >> 32));
        sidx[b * PRE + r] = n;
        ssc[b * PRE + r] = sc;
        const float* bp = box + ((size_t)b * NN + n) * 7;
        float x = bp[0], y = bp[1], dx = bp[3], dy = bp[4];
        float* bfb = bf + (size_t)b * 5 * PRE;
        bfb[0 * PRE + r] = x - dx * 0.5f;
        bfb[1 * PRE + r] = x + dx * 0.5f;
        bfb[2 * PRE + r] = y - dy * 0.5f;
        bfb[3 * PRE + r] = y + dy * 0.5f;
        bfb[4 * PRE + r] = dx * dy;
    }
}

// 4) suppression rows [0,ROWS_A) x cols [0, RW*64): one wave per row,
//    word w = __ballot over lanes at j = w*64+lane (coalesced bf reads).
__global__ void k_iou(const float* __restrict__ bf, u64* __restrict__ sup) {
    const int bpi = ROWS_A / 4;              // blocks per item (4 waves/block)
    int b = blockIdx.x / bpi;
    int wave = threadIdx.x >> 6;
    int lane = threadIdx.x & 63;
    int i = (blockIdx.x % bpi) * 4 + wave;
    const float* bfb = bf + (size_t)b * 5 * PRE;
    float x1 = bfb[0 * PRE + i], x2 = bfb[1 * PRE + i];
    float y1 = bfb[2 * PRE + i], y2 = bfb[3 * PRE + i];
    float ar = bfb[4 * PRE + i];
    u64 myword = 0;
    for (int jw = 0; jw < RW; ++jw) {
        int j = jw * 64 + lane;
        float jx1 = bfb[0 * PRE + j], jx2 = bfb[1 * PRE + j];
        float jy1 = bfb[2 * PRE + j], jy2 = bfb[3 * PRE + j];
        float jar = bfb[4 * PRE + j];
        float ix = fminf(x2, jx2) - fmaxf(x1, jx1);
        ix = fmaxf(ix, 0.0f);
        float iy = fminf(y2, jy2) - fmaxf(y1, jy1);
        iy = fmaxf(iy, 0.0f);
        float inter = __fmul_rn(ix, iy);            // block FMA contraction (match np rounding)
        float uni = (ar + jar) - inter;
        float iou = inter / fmaxf(uni, 1e-6f);
        u64 bal = __ballot((iou > TH) && (j > i));
        if (jw == lane) myword = bal;
    }
    if (lane < RW) sup[((size_t)b * PRE + i) * 64 + lane] = myword;
}

// 5) fixpoint NMS + output (replaces the serial wave-scan):
//    Iterate K_{t+1}[j] = !(exists i: K_t[i] & sup[i][j]) from all-ones. sup[i][j]=0 for
//    j<=i, so ANY fixpoint satisfies the greedy recurrence exactly => fixpoint == greedy
//    (unique by induction on j). Chain depth on this data ~2-4 => ~3-5 Jacobi iterations,
//    each a parallel 768x12-word OR-reduce. Exact convergence check; cap 48 iters.
//    Keep bits for rows<ROWS_A are FINAL (suppressors only earlier rows); if
//    kept>=POST -> output directly, else serial full-PRE fallback (exact, rare).
__global__ void __launch_bounds__(512) k_nmsout(const u64* __restrict__ sup,
                                                const int* __restrict__ sidx,
                                                const float* __restrict__ ssc,
                                                const float* __restrict__ box,
                                                const float* __restrict__ cls,
                                                const float* __restrict__ bf,
                                                float* __restrict__ out) {
    int b = blockIdx.x;
    int tid = threadIdx.x;
    __shared__ u64 km[64];
    __shared__ uint32_t wpre[65];
    __shared__ u64 keepw[RW], nremw[RW];
    __shared__ int s_changed, s_done;
    const u64* sb = sup + (size_t)b * PRE * 64;
    const float* bfb = bf + (size_t)b * 5 * PRE;

    if (tid < RW) keepw[tid] = ~0ull;
    if (tid == 0) s_done = 0;
    __syncthreads();
    for (int it = 0; it < 48; ++it) {
        if (tid < RW) nremw[tid] = 0;
        if (tid == 0) s_changed = 0;
        __syncthreads();
        // 768 tasks: (word w, 12-row chunk); threads cover tasks tid and tid+512
        for (int tau = tid; tau < ROWS_A; tau += 512) {
            int w = tau % RW;
            int r0 = (tau / RW) * 12;
            u64 acc = 0;
#pragma unroll
            for (int rr = 0; rr < 12; ++rr) {
                int r = r0 + rr;
                if ((keepw[r >> 6] >> (r & 63)) & 1ull)
                    acc |= sb[(size_t)r * 64 + w];
            }
            if (acc) atomicOr(&nremw[w], acc);
        }
        __syncthreads();
        if (tid < RW) {
            u64 nk = ~nremw[tid];
            if (nk != keepw[tid]) { s_changed = 1; keepw[tid] = nk; }
        }
        __syncthreads();
        if (!s_changed) { if (tid == 0) s_done = 1; break; }   // uniform exit
    }
    __syncthreads();

    // kept count over rows < ROWS_A
    if (tid == 0) {
        uint32_t c = 0;
        for (int w = 0; w < RW; ++w) c += (uint32_t)__popcll(keepw[w]);
        s_changed = (s_done && c >= POST) ? 1 : 0;   // reuse as "fast path ok"
    }
    __syncthreads();

    if (s_changed) {
        if (tid < 64) km[tid] = (tid < RW) ? keepw[tid] : 0ull;
        __syncthreads();
    } else {
        // serial greedy fallback over all PRE ranked boxes (exact reference semantics)
        if (tid < 64) km[tid] = ~0ull;
        __syncthreads();
        for (int i = 0; i < PRE - 1; ++i) {
            if ((km[i >> 6] >> (i & 63)) & 1ull) {
                float x1 = bfb[0 * PRE + i], x2 = bfb[1 * PRE + i];
                float y1 = bfb[2 * PRE + i], y2 = bfb[3 * PRE + i];
                float ar = bfb[4 * PRE + i];
                for (int j = i + 1 + tid; j < PRE; j += 512) {
                    float ix = fminf(x2, bfb[1 * PRE + j]) - fmaxf(x1, bfb[0 * PRE + j]);
                    ix = fmaxf(ix, 0.0f);
                    float iy = fminf(y2, bfb[3 * PRE + j]) - fmaxf(y1, bfb[2 * PRE + j]);
                    iy = fmaxf(iy, 0.0f);
                    float inter = __fmul_rn(ix, iy);
                    float uni = (ar + bfb[4 * PRE + j]) - inter;
                    float iou = inter / fmaxf(uni, 1e-6f);
                    if (iou > TH) atomicAnd(&km[j >> 6], ~(1ull << (j & 63)));
                }
            }
            __syncthreads();
        }
    }

    if (tid == 0) {
        uint32_t c = 0;
        for (int w = 0; w < 64; ++w) { wpre[w] = c; c += (uint32_t)__popcll(km[w]); }
        wpre[64] = c;
    }
    __syncthreads();
    uint32_t nkeep = wpre[64];
    for (int r = tid; r < PRE; r += 512) {
        int w = r >> 6, bit = r & 63;
        u64 word = km[w];
        bool kept = (word >> bit) & 1ull;
        u64 mask = bit ? ((1ull << bit) - 1ull) : 0ull;
        uint32_t before = wpre[w] + (uint32_t)__popcll(word & mask);
        uint32_t d = kept ? before : (nkeep + (uint32_t)r - before);
        if (d < POST) {
            float* ro = out + ((size_t)b * POST + d) * 7;
            float* so = out + (size_t)BB * POST * 7 + b * POST + d;
            float* lo = out + (size_t)BB * POST * 8 + b * POST + d;
            if (kept) {
                int n = sidx[b * PRE + r];
                const float* bp = box + ((size_t)b * NN + n) * 7;
#pragma unroll
                for (int t = 0; t < 7; ++t) ro[t] = bp[t];
                *so = ssc[b * PRE + r];
                const float* cp = cls + ((size_t)b * NN + n) * CC;
                float c0 = cp[0], c1 = cp[1], c2 = cp[2];
                int lbl = 0; float bst = c0;
                if (c1 > bst) { bst = c1; lbl = 1; }
                if (c2 > bst) { lbl = 2; }
                *lo = (float)(lbl + 1);
            } else {
#pragma unroll
                for (int t = 0; t < 7; ++t) ro[t] = 0.0f;
                *so = 0.0f;
                *lo = 1.0f;
            }
        }
    }
}

extern "C" void kernel_launch(void* const* d_in, const int* in_sizes, int n_in,
                              void* d_out, int out_size, void* d_ws, size_t ws_size,
                              hipStream_t stream) {
    const float* cls = (const float*)d_in[0];   // (4, 32768, 3)
    const float* box = (const float*)d_in[1];   // (4, 32768, 7)
    float* out = (float*)d_out;                 // 18432 floats

    char* ws = (char*)d_ws;
    const size_t MB = 1024 * 1024;
    // sup occupies [0, 8MB); hist/cand/selk alias inside it.
    // k_iou writes item b bytes [b*2MB, b*2MB + 384KB):
    //   item0 [0,384K): empty; item1 [2M,2.38M): hist_c+cand (dead after k_rankscatter);
    //   item2/3: empty. hist_f [1M,2M) and selk [3M,3.125M) untouched (and dead by then).
    size_t OFF_SUP   = 0;
    size_t OFF_HISTF = 1 * MB;                   // 1 MB  (4 x 65536 x 4)
    size_t OFF_HISTC = 2 * MB;                   // 4 KB  (4 x 256 x 4), contiguous with hist_f
    size_t OFF_CAND  = 2 * MB + 4096;            // 128 KB (4 x 4096 x 8)
    size_t OFF_SELK  = 3 * MB;                   // 128 KB
    size_t OFF_BF    = 8 * MB;                   // 320 KB
    size_t OFF_SIDX  = OFF_BF + (size_t)BB * 5 * PRE * 4;
    size_t OFF_SSC   = OFF_SIDX + (size_t)BB * PRE * 4;
    size_t OFF_SCAL  = OFF_SSC + (size_t)BB * PRE * 4;   // cnt[4], ccnt[4], pad

    u64*      sup    = (u64*)(ws + OFF_SUP);
    uint32_t* hist_f = (uint32_t*)(ws + OFF_HISTF);
    uint32_t* hist_c = (uint32_t*)(ws + OFF_HISTC);
    u64*      cand   = (u64*)(ws + OFF_CAND);
    u64*      selk   = (u64*)(ws + OFF_SELK);
    float*    bf     = (float*)(ws + OFF_BF);
    int*      sidx   = (int*)(ws + OFF_SIDX);
    float*    ssc    = (float*)(ws + OFF_SSC);
    uint32_t* scal   = (uint32_t*)(ws + OFF_SCAL);
    uint32_t* cnt    = scal;
    uint32_t* ccnt   = scal + 4;

    // 6-dispatch chain:
    hipMemsetAsync(ws + OFF_HISTF, 0, MB + 4096, stream);          // hist_f + hist_c
    k_hist<<<(BB * NN) / 256, 256, 0, stream>>>(cls, hist_f, hist_c, scal);
    k_collect<<<(BB * NN) / 256, 256, 0, stream>>>(cls, hist_c, hist_f, cnt, ccnt, selk, cand);
    k_rankscatter<<<BB * RS_BPI, 256, 0, stream>>>(selk, cand, cnt, ccnt, box, sidx, ssc, bf);
    k_iou<<<(ROWS_A / 4) * BB, 256, 0, stream>>>(bf, sup);
    k_nmsout<<<BB, 512, 0, stream>>>(sup, sidx, ssc, box, cls, bf, out);
}